// Round 4
// baseline (1000.792 us; speedup 1.0000x reference)
//
#include <hip/hip_runtime.h>
#include <math.h>

#define N_B 4
#define SEQ 2048
#define DM  512
#define H_N 8
#define DH  64

// C[m,c] = sum_k A[m,k] * W[c,k] + bias[c]   (all fp32)
// MODE 0: store fp32 split-head scatter: dst[((n*H + c%8)*SEQ + s)*64 + c/8]
// MODE 1: store fp32 plain: dst[m*DM + c]
template<int MODE>
__global__ __launch_bounds__(256)
void gemm_k(const float* __restrict__ A, const float* __restrict__ W,
            const float* __restrict__ bias, float* __restrict__ dst)
{
    __shared__ float As[16][68];
    __shared__ float Bs[16][68];
    const int t  = threadIdx.x;
    const int tx = t & 15;        // col group
    const int ty = t >> 4;        // row group
    const int bn = blockIdx.x;    // 0..7
    const int bm = blockIdx.y;    // 0..127
    const int row0 = bm * 64, col0 = bn * 64;

    const int ar = t >> 2;        // 0..63 tile row for staging
    const int ac = (t & 3) * 4;   // k offset 0,4,8,12

    float acc[4][4];
    #pragma unroll
    for (int i = 0; i < 4; i++)
        #pragma unroll
        for (int j = 0; j < 4; j++) acc[i][j] = 0.f;

    for (int k0 = 0; k0 < DM; k0 += 16) {
        {
            float4 u = *(const float4*)(A + (size_t)(row0 + ar) * DM + k0 + ac);
            As[ac + 0][ar] = u.x;
            As[ac + 1][ar] = u.y;
            As[ac + 2][ar] = u.z;
            As[ac + 3][ar] = u.w;
        }
        {
            float4 u = *(const float4*)(W + (size_t)(col0 + ar) * DM + k0 + ac);
            Bs[ac + 0][ar] = u.x;
            Bs[ac + 1][ar] = u.y;
            Bs[ac + 2][ar] = u.z;
            Bs[ac + 3][ar] = u.w;
        }
        __syncthreads();
        #pragma unroll
        for (int kk = 0; kk < 16; kk++) {
            float av[4], bv[4];
            *(float4*)av = *(const float4*)&As[kk][ty * 4];
            *(float4*)bv = *(const float4*)&Bs[kk][tx * 4];
            #pragma unroll
            for (int i = 0; i < 4; i++)
                #pragma unroll
                for (int j = 0; j < 4; j++)
                    acc[i][j] += av[i] * bv[j];
        }
        __syncthreads();
    }

    float bv[4];
    #pragma unroll
    for (int j = 0; j < 4; j++) bv[j] = bias[col0 + tx * 4 + j];

    if (MODE == 0) {
        #pragma unroll
        for (int i = 0; i < 4; i++) {
            int m = row0 + ty * 4 + i;
            int n = m >> 11, s = m & 2047;
            #pragma unroll
            for (int j = 0; j < 4; j++) {
                int c = col0 + tx * 4 + j;
                int h = c & 7, dh = c >> 3;
                dst[(((size_t)(n * H_N + h)) * SEQ + s) * DH + dh] = acc[i][j] + bv[j];
            }
        }
    } else {
        #pragma unroll
        for (int i = 0; i < 4; i++) {
            int m = row0 + ty * 4 + i;
            #pragma unroll
            for (int j = 0; j < 4; j++) {
                int c = col0 + tx * 4 + j;
                dst[(size_t)m * DM + c] = acc[i][j] + bv[j];
            }
        }
    }
}

// One block = (n, h, 32 query rows). Flash-style online softmax over 64-key tiles.
__global__ __launch_bounds__(256)
void attn_k(const float* __restrict__ qw, const float* __restrict__ kw,
            const float* __restrict__ vw, const float* __restrict__ lsc,
            const float* __restrict__ rpe, float* __restrict__ ctx)
{
    __shared__ float q_s[32][68];
    __shared__ float kT_s[64][68];   // [d][key]
    __shared__ float v_s[64][68];    // [key][d]
    __shared__ float p_s[32][68];
    __shared__ float bias_s[96];
    __shared__ float scale_sh;

    const int t  = threadIdx.x;
    const int qt = blockIdx.x;   // 0..63
    const int h  = blockIdx.y;
    const int n  = blockIdx.z;
    const int q0 = qt * 32;

    const size_t headoff = ((size_t)(n * H_N + h)) * SEQ * DH;
    const float* qh = qw + headoff;
    const float* kh = kw + headoff;
    const float* vh = vw + headoff;

    if (t == 0) {
        float ls = lsc[h];
        const float lm = 4.60517018598809136804f;  // log(100)
        if (ls > lm) ls = lm;
        scale_sh = __expf(ls) * 0.04419417382415921757f;  // 1/sqrt(512)
    }

    {   // stage q tile (32 x 64)
        int r  = t >> 3;          // 0..31
        int c4 = (t & 7) * 8;     // 0..56
        float4 u0 = *(const float4*)(qh + (size_t)(q0 + r) * DH + c4);
        float4 u1 = *(const float4*)(qh + (size_t)(q0 + r) * DH + c4 + 4);
        *(float4*)&q_s[r][c4]     = u0;
        *(float4*)&q_s[r][c4 + 4] = u1;
    }
    __syncthreads();

    const float scale = scale_sh;
    const int cg = t & 15;   // key-group (score) / dim-group (output)
    const int rg = t >> 4;   // 0..15 -> rows 2rg, 2rg+1

    float m_run[2] = {-1e30f, -1e30f};
    float l_run[2] = {0.f, 0.f};
    float o[2][4];
    float alpha[2];
    #pragma unroll
    for (int rr = 0; rr < 2; rr++)
        #pragma unroll
        for (int i = 0; i < 4; i++) o[rr][i] = 0.f;

    for (int j0 = 0; j0 < SEQ; j0 += 64) {
        __syncthreads();  // previous-iter readers of kT_s/v_s/bias_s done
        {   // stage k (transposed) and v
            int key = t >> 2;          // 0..63
            int d0  = (t & 3) * 16;    // 0,16,32,48
            const float* ksrc = kh + (size_t)(j0 + key) * DH + d0;
            const float* vsrc = vh + (size_t)(j0 + key) * DH + d0;
            #pragma unroll
            for (int i = 0; i < 4; i++) {
                float4 kv = *(const float4*)(ksrc + i * 4);
                kT_s[d0 + i * 4 + 0][key] = kv.x;
                kT_s[d0 + i * 4 + 1][key] = kv.y;
                kT_s[d0 + i * 4 + 2][key] = kv.z;
                kT_s[d0 + i * 4 + 3][key] = kv.w;
                *(float4*)&v_s[key][d0 + i * 4] = *(const float4*)(vsrc + i * 4);
            }
        }
        if (t < 95) {
            int idx = q0 - j0 + 1984 + t;  // in [0, 4094]
            float x = rpe[idx * H_N + h];
            bias_s[t] = 1.0f / (1.0f + __expf(-x));
        }
        __syncthreads();

        // ---- score phase: rows {2rg, 2rg+1} x keys {4cg..4cg+3}
        float s[2][4];
        #pragma unroll
        for (int rr = 0; rr < 2; rr++)
            #pragma unroll
            for (int j = 0; j < 4; j++) s[rr][j] = 0.f;

        #pragma unroll
        for (int d0 = 0; d0 < 64; d0 += 4) {
            float qa[2][4];
            *(float4*)qa[0] = *(const float4*)&q_s[2 * rg + 0][d0];
            *(float4*)qa[1] = *(const float4*)&q_s[2 * rg + 1][d0];
            #pragma unroll
            for (int i = 0; i < 4; i++) {
                float kv[4];
                *(float4*)kv = *(const float4*)&kT_s[d0 + i][4 * cg];
                #pragma unroll
                for (int j = 0; j < 4; j++) {
                    s[0][j] += qa[0][i] * kv[j];
                    s[1][j] += qa[1][i] * kv[j];
                }
            }
        }

        // scale + bias, tile max
        float mx[2];
        #pragma unroll
        for (int rr = 0; rr < 2; rr++) {
            int r = 2 * rg + rr;
            float lm2 = -1e30f;
            #pragma unroll
            for (int j = 0; j < 4; j++) {
                float b = bias_s[63 + r - (4 * cg + j)];
                s[rr][j] = s[rr][j] * scale + b;
                lm2 = fmaxf(lm2, s[rr][j]);
            }
            mx[rr] = lm2;
        }
        #pragma unroll
        for (int off = 1; off < 16; off <<= 1) {
            mx[0] = fmaxf(mx[0], __shfl_xor(mx[0], off));
            mx[1] = fmaxf(mx[1], __shfl_xor(mx[1], off));
        }

        float psum[2];
        #pragma unroll
        for (int rr = 0; rr < 2; rr++) {
            float mnew = fmaxf(m_run[rr], mx[rr]);
            alpha[rr]  = __expf(m_run[rr] - mnew);
            m_run[rr]  = mnew;
            float ps = 0.f;
            #pragma unroll
            for (int j = 0; j < 4; j++) {
                float p = __expf(s[rr][j] - mnew);
                s[rr][j] = p;
                ps += p;
            }
            psum[rr] = ps;
        }
        #pragma unroll
        for (int off = 1; off < 16; off <<= 1) {
            psum[0] += __shfl_xor(psum[0], off);
            psum[1] += __shfl_xor(psum[1], off);
        }
        #pragma unroll
        for (int rr = 0; rr < 2; rr++)
            l_run[rr] = l_run[rr] * alpha[rr] + psum[rr];

        *(float4*)&p_s[2 * rg + 0][4 * cg] = make_float4(s[0][0], s[0][1], s[0][2], s[0][3]);
        *(float4*)&p_s[2 * rg + 1][4 * cg] = make_float4(s[1][0], s[1][1], s[1][2], s[1][3]);
        __syncthreads();

        // ---- output phase: rows {2rg, 2rg+1} x dims {4cg..4cg+3}
        #pragma unroll
        for (int rr = 0; rr < 2; rr++)
            #pragma unroll
            for (int i = 0; i < 4; i++) o[rr][i] *= alpha[rr];

        #pragma unroll
        for (int jj0 = 0; jj0 < 64; jj0 += 4) {
            float pa[2][4];
            *(float4*)pa[0] = *(const float4*)&p_s[2 * rg + 0][jj0];
            *(float4*)pa[1] = *(const float4*)&p_s[2 * rg + 1][jj0];
            #pragma unroll
            for (int j = 0; j < 4; j++) {
                float vv[4];
                *(float4*)vv = *(const float4*)&v_s[jj0 + j][4 * cg];
                #pragma unroll
                for (int i = 0; i < 4; i++) {
                    o[0][i] += pa[0][j] * vv[i];
                    o[1][i] += pa[1][j] * vv[i];
                }
            }
        }
    }

    // epilogue: normalize, write merged-head ctx (N, S, 512) fp32
    #pragma unroll
    for (int rr = 0; rr < 2; rr++) {
        float inv = 1.0f / l_run[rr];
        int r = q0 + 2 * rg + rr;
        float4 res = make_float4(o[rr][0] * inv, o[rr][1] * inv, o[rr][2] * inv, o[rr][3] * inv);
        *(float4*)(ctx + ((size_t)(n * SEQ + r)) * DM + h * DH + 4 * cg) = res;
    }
}

extern "C" void kernel_launch(void* const* d_in, const int* in_sizes, int n_in,
                              void* d_out, int out_size, void* d_ws, size_t ws_size,
                              hipStream_t stream) {
    const float* query = (const float*)d_in[0];
    const float* Wq  = (const float*)d_in[1];
    const float* bq  = (const float*)d_in[2];
    const float* Wk  = (const float*)d_in[3];
    const float* bk  = (const float*)d_in[4];
    const float* Wv  = (const float*)d_in[5];
    const float* bv  = (const float*)d_in[6];
    const float* Wp  = (const float*)d_in[7];
    const float* bp  = (const float*)d_in[8];
    const float* lsc = (const float*)d_in[9];
    const float* rpe = (const float*)d_in[10];

    float* ws  = (float*)d_ws;
    const size_t TSZ = (size_t)N_B * H_N * SEQ * DH;  // 4,194,304
    float* qws = ws;
    float* kws = ws + TSZ;
    float* vws = ws + 2 * TSZ;
    float* ctx = ws + 3 * TSZ;

    dim3 gg(DM / 64, (N_B * SEQ) / 64);  // (8, 128)
    gemm_k<0><<<gg, 256, 0, stream>>>(query, Wq, bq, qws);
    gemm_k<0><<<gg, 256, 0, stream>>>(query, Wk, bk, kws);
    gemm_k<0><<<gg, 256, 0, stream>>>(query, Wv, bv, vws);

    dim3 ga(SEQ / 32, H_N, N_B);  // (64, 8, 4)
    attn_k<<<ga, 256, 0, stream>>>(qws, kws, vws, lsc, rpe, ctx);

    gemm_k<1><<<gg, 256, 0, stream>>>(ctx, Wp, bp, (float*)d_out);
}

// Round 5
// 460.354 us; speedup vs baseline: 2.1740x; 2.1740x over previous
//
#include <hip/hip_runtime.h>
#include <math.h>

#define N_B 4
#define SEQ 2048
#define DM  512
#define H_N 8
#define DH  64

typedef unsigned short ushort_t;
typedef __attribute__((ext_vector_type(8))) short short8_t;
typedef __attribute__((ext_vector_type(4))) float float4_t;

__device__ __forceinline__ ushort_t f2bf(float f) {
    unsigned int x = __float_as_uint(f);
    unsigned int lsb = (x >> 16) & 1u;
    x += 0x7fffu + lsb;
    return (ushort_t)(x >> 16);
}

// C[m,c] = sum_k A[m,k] * W[c,k] + bias[c]   (A,W fp32)
// MODE 0: bf16 split-head scatter: dst[((n*H + c%8)*SEQ + s)*64 + c/8]
// MODE 2: bf16 split-head TRANSPOSED: dst[((n*H + c%8)*64 + c/8)*SEQ + s]
// MODE 1: fp32 plain: dst[m*DM + c]
template<int MODE>
__global__ __launch_bounds__(256)
void gemm_k(const float* __restrict__ A, const float* __restrict__ W,
            const float* __restrict__ bias, void* __restrict__ Dp)
{
    __shared__ float As[16][68];
    __shared__ float Bs[16][68];
    const int t  = threadIdx.x;
    const int tx = t & 15;
    const int ty = t >> 4;
    const int bn = blockIdx.x;
    const int bm = blockIdx.y;
    const int row0 = bm * 64, col0 = bn * 64;

    const int ar = t >> 2;
    const int ac = (t & 3) * 4;

    float acc[4][4];
    #pragma unroll
    for (int i = 0; i < 4; i++)
        #pragma unroll
        for (int j = 0; j < 4; j++) acc[i][j] = 0.f;

    for (int k0 = 0; k0 < DM; k0 += 16) {
        {
            float4 u = *(const float4*)(A + (size_t)(row0 + ar) * DM + k0 + ac);
            As[ac + 0][ar] = u.x;  As[ac + 1][ar] = u.y;
            As[ac + 2][ar] = u.z;  As[ac + 3][ar] = u.w;
        }
        {
            float4 u = *(const float4*)(W + (size_t)(col0 + ar) * DM + k0 + ac);
            Bs[ac + 0][ar] = u.x;  Bs[ac + 1][ar] = u.y;
            Bs[ac + 2][ar] = u.z;  Bs[ac + 3][ar] = u.w;
        }
        __syncthreads();
        #pragma unroll
        for (int kk = 0; kk < 16; kk++) {
            float av[4], bv[4];
            *(float4*)av = *(const float4*)&As[kk][ty * 4];
            *(float4*)bv = *(const float4*)&Bs[kk][tx * 4];
            #pragma unroll
            for (int i = 0; i < 4; i++)
                #pragma unroll
                for (int j = 0; j < 4; j++)
                    acc[i][j] += av[i] * bv[j];
        }
        __syncthreads();
    }

    float bv[4];
    #pragma unroll
    for (int j = 0; j < 4; j++) bv[j] = bias[col0 + tx * 4 + j];

    if (MODE == 0) {
        ushort_t* dst = (ushort_t*)Dp;
        #pragma unroll
        for (int i = 0; i < 4; i++) {
            int m = row0 + ty * 4 + i;
            int n = m >> 11, s = m & 2047;
            #pragma unroll
            for (int j = 0; j < 4; j++) {
                int c = col0 + tx * 4 + j;
                int h = c & 7, dh = c >> 3;
                dst[(((size_t)(n * H_N + h)) * SEQ + s) * DH + dh] = f2bf(acc[i][j] + bv[j]);
            }
        }
    } else if (MODE == 2) {
        ushort_t* dst = (ushort_t*)Dp;
        #pragma unroll
        for (int i = 0; i < 4; i++) {
            int m = row0 + ty * 4 + i;
            int n = m >> 11, s = m & 2047;
            #pragma unroll
            for (int j = 0; j < 4; j++) {
                int c = col0 + tx * 4 + j;
                int h = c & 7, dh = c >> 3;
                dst[(((size_t)(n * H_N + h)) * DH + dh) * SEQ + s] = f2bf(acc[i][j] + bv[j]);
            }
        }
    } else {
        float* dst = (float*)Dp;
        #pragma unroll
        for (int i = 0; i < 4; i++) {
            int m = row0 + ty * 4 + i;
            #pragma unroll
            for (int j = 0; j < 4; j++) {
                int c = col0 + tx * 4 + j;
                dst[(size_t)m * DM + c] = acc[i][j] + bv[j];
            }
        }
    }
}

// MFMA flash attention. Block = (n, h, 64 q-rows); 4 waves, wave owns 16 q-rows.
// q,k: bf16 [n,h,s,64]; vt: bf16 [n,h,64,s]; ctx out fp32 [n,s,512].
__global__ __launch_bounds__(256)
void attn_k(const ushort_t* __restrict__ qw, const ushort_t* __restrict__ kw,
            const ushort_t* __restrict__ vt, const float* __restrict__ lsc,
            const float* __restrict__ rpe, float* __restrict__ ctx)
{
    __shared__ __align__(16) ushort_t K_s[64][72];   // [key][dim], 144B row = 16B-aligned
    __shared__ __align__(16) ushort_t VT_s[64][72];  // [dim][key]
    __shared__ __align__(16) ushort_t P_s[4][16][80];// per-wave [qrow][key]
    __shared__ float bias_s[128];

    const int t     = threadIdx.x;
    const int wid   = t >> 6;
    const int lane  = t & 63;
    const int lan16 = lane & 15;
    const int quad  = lane >> 4;

    const int qt = blockIdx.x;    // 0..31
    const int h  = blockIdx.y;
    const int n  = blockIdx.z;
    const int q0 = qt * 64;

    const size_t headoff = ((size_t)(n * H_N + h)) * SEQ * DH;
    const ushort_t* qh  = qw + headoff;
    const ushort_t* kh  = kw + headoff;
    const ushort_t* vth = vt + headoff;   // row dh: [dh*SEQ + s]

    // per-thread scale (cheap, avoids a broadcast barrier)
    float ls = lsc[h];
    const float lm = 4.60517018598809136804f;   // log(100)
    if (ls > lm) ls = lm;
    const float scale = __expf(ls) * 0.04419417382415921757f;  // 1/sqrt(512)

    // Q A-frags: A[m=lan16][k=quad*8+j], frag f covers dims 32f..32f+31
    short8_t qa0, qa1;
    {
        const ushort_t* src = qh + (size_t)(q0 + wid * 16 + lan16) * DH + quad * 8;
        qa0 = *(const short8_t*)(src);
        qa1 = *(const short8_t*)(src + 32);
    }

    float m_run[4], l_run[4];
    #pragma unroll
    for (int r = 0; r < 4; r++) { m_run[r] = -1e30f; l_run[r] = 0.f; }
    float4_t o[4];
    #pragma unroll
    for (int s = 0; s < 4; s++) o[s] = (float4_t){0.f, 0.f, 0.f, 0.f};

    const int key_st = t >> 2;        // staging row 0..63
    const int part   = t & 3;         // 16-element chunk

    for (int j0 = 0; j0 < SEQ; j0 += 64) {
        __syncthreads();   // previous-iteration readers of K_s/VT_s/bias_s done
        {   // stage K tile (64 keys x 64 dims) and VT tile (64 dims x 64 keys)
            const ushort_t* ksrc = kh + (size_t)(j0 + key_st) * DH + part * 16;
            *(uint4*)&K_s[key_st][part * 16]     = *(const uint4*)(ksrc);
            *(uint4*)&K_s[key_st][part * 16 + 8] = *(const uint4*)(ksrc + 8);
            const ushort_t* vsrc = vth + (size_t)key_st * SEQ + j0 + part * 16;
            *(uint4*)&VT_s[key_st][part * 16]     = *(const uint4*)(vsrc);
            *(uint4*)&VT_s[key_st][part * 16 + 8] = *(const uint4*)(vsrc + 8);
        }
        if (t < 127) {
            int idx = q0 - j0 + 1984 + t;            // in [0, 4094]
            float x = rpe[idx * H_N + h];
            bias_s[t] = 1.0f / (1.0f + __expf(-x));  // idx_local = (r-c)-(q0-j0-63)
        }
        __syncthreads();

        // ---- QK^T: S[16 x 64] per wave ----
        float4_t sc[4];
        #pragma unroll
        for (int sub = 0; sub < 4; sub++) {
            const ushort_t* kb = &K_s[sub * 16 + lan16][quad * 8];
            short8_t kb0 = *(const short8_t*)(kb);
            short8_t kb1 = *(const short8_t*)(kb + 32);
            float4_t a = (float4_t){0.f, 0.f, 0.f, 0.f};
            a = __builtin_amdgcn_mfma_f32_16x16x32_bf16(qa0, kb0, a, 0, 0, 0);
            a = __builtin_amdgcn_mfma_f32_16x16x32_bf16(qa1, kb1, a, 0, 0, 0);
            sc[sub] = a;
        }

        // ---- softmax (fp32). Row r = wid*16 + quad*4 + reg, col = sub*16 + lan16
        float sval[4][4];
        float mx[4] = {-1e30f, -1e30f, -1e30f, -1e30f};
        const int rbase = quad * 4;              // local row within wave tile
        #pragma unroll
        for (int sub = 0; sub < 4; sub++) {
            int cl = sub * 16 + lan16;
            #pragma unroll
            for (int reg = 0; reg < 4; reg++) {
                int rl = wid * 16 + rbase + reg;
                float v = sc[sub][reg] * scale + bias_s[rl - cl + 63];
                sval[sub][reg] = v;
                mx[reg] = fmaxf(mx[reg], v);
            }
        }
        #pragma unroll
        for (int off = 1; off < 16; off <<= 1) {
            #pragma unroll
            for (int reg = 0; reg < 4; reg++)
                mx[reg] = fmaxf(mx[reg], __shfl_xor(mx[reg], off));
        }
        float alpha[4], ps[4];
        #pragma unroll
        for (int reg = 0; reg < 4; reg++) {
            float mnew = fmaxf(m_run[reg], mx[reg]);
            alpha[reg] = __expf(m_run[reg] - mnew);
            m_run[reg] = mnew;
            ps[reg] = 0.f;
        }
        #pragma unroll
        for (int sub = 0; sub < 4; sub++)
            #pragma unroll
            for (int reg = 0; reg < 4; reg++) {
                float p = __expf(sval[sub][reg] - m_run[reg]);
                sval[sub][reg] = p;
                ps[reg] += p;
            }
        #pragma unroll
        for (int off = 1; off < 16; off <<= 1) {
            #pragma unroll
            for (int reg = 0; reg < 4; reg++)
                ps[reg] += __shfl_xor(ps[reg], off);
        }
        #pragma unroll
        for (int reg = 0; reg < 4; reg++)
            l_run[reg] = l_run[reg] * alpha[reg] + ps[reg];

        // ---- P: C-layout -> LDS (bf16) -> A-layout ----
        #pragma unroll
        for (int sub = 0; sub < 4; sub++)
            #pragma unroll
            for (int reg = 0; reg < 4; reg++)
                P_s[wid][rbase + reg][sub * 16 + lan16] = f2bf(sval[sub][reg]);
        __syncthreads();

        // ---- PV: O[16 x 64] per wave ----
        short8_t pa0, pa1;
        {
            const ushort_t* pp = &P_s[wid][lan16][quad * 8];
            pa0 = *(const short8_t*)(pp);
            pa1 = *(const short8_t*)(pp + 32);
        }
        #pragma unroll
        for (int sub = 0; sub < 4; sub++) {
            const ushort_t* vb = &VT_s[sub * 16 + lan16][quad * 8];
            short8_t vb0 = *(const short8_t*)(vb);
            short8_t vb1 = *(const short8_t*)(vb + 32);
            float4_t a = o[sub];
            #pragma unroll
            for (int reg = 0; reg < 4; reg++) a[reg] *= alpha[reg];
            a = __builtin_amdgcn_mfma_f32_16x16x32_bf16(pa0, vb0, a, 0, 0, 0);
            a = __builtin_amdgcn_mfma_f32_16x16x32_bf16(pa1, vb1, a, 0, 0, 0);
            o[sub] = a;
        }
    }

    // epilogue: normalize, write fp32 ctx (N, S, 512)
    float inv[4];
    #pragma unroll
    for (int reg = 0; reg < 4; reg++) inv[reg] = 1.0f / l_run[reg];
    #pragma unroll
    for (int sub = 0; sub < 4; sub++) {
        #pragma unroll
        for (int reg = 0; reg < 4; reg++) {
            int row = q0 + wid * 16 + quad * 4 + reg;
            ctx[((size_t)n * SEQ + row) * DM + h * DH + sub * 16 + lan16] = o[sub][reg] * inv[reg];
        }
    }
}

extern "C" void kernel_launch(void* const* d_in, const int* in_sizes, int n_in,
                              void* d_out, int out_size, void* d_ws, size_t ws_size,
                              hipStream_t stream) {
    const float* query = (const float*)d_in[0];
    const float* Wq  = (const float*)d_in[1];
    const float* bq  = (const float*)d_in[2];
    const float* Wk  = (const float*)d_in[3];
    const float* bk  = (const float*)d_in[4];
    const float* Wv  = (const float*)d_in[5];
    const float* bv  = (const float*)d_in[6];
    const float* Wp  = (const float*)d_in[7];
    const float* bp  = (const float*)d_in[8];
    const float* lsc = (const float*)d_in[9];
    const float* rpe = (const float*)d_in[10];

    const size_t TSZ = (size_t)N_B * H_N * SEQ * DH;   // 4,194,304 elements
    char* ws = (char*)d_ws;
    ushort_t* qws = (ushort_t*)(ws);                   // 8.4 MB
    ushort_t* kws = (ushort_t*)(ws + TSZ * 2);         // 8.4 MB
    ushort_t* vtw = (ushort_t*)(ws + TSZ * 4);         // 8.4 MB
    float*    ctx = (float*)   (ws + TSZ * 6);         // 16.8 MB fp32

    dim3 gg(DM / 64, (N_B * SEQ) / 64);  // (8, 128)
    gemm_k<0><<<gg, 256, 0, stream>>>(query, Wq, bq, (void*)qws);
    gemm_k<0><<<gg, 256, 0, stream>>>(query, Wk, bk, (void*)kws);
    gemm_k<2><<<gg, 256, 0, stream>>>(query, Wv, bv, (void*)vtw);

    dim3 ga(SEQ / 64, H_N, N_B);  // (32, 8, 4)
    attn_k<<<ga, 256, 0, stream>>>(qws, kws, vtw, lsc, rpe, ctx);

    gemm_k<1><<<gg, 256, 0, stream>>>(ctx, Wp, bp, d_out);
}

// Round 7
// 322.665 us; speedup vs baseline: 3.1016x; 1.4267x over previous
//
#include <hip/hip_runtime.h>
#include <math.h>

#define N_B 4
#define SEQ 2048
#define DM  512
#define H_N 8
#define DH  64

typedef unsigned short ushort_t;
typedef __attribute__((ext_vector_type(8))) short short8_t;
typedef __attribute__((ext_vector_type(4))) float float4_t;

__device__ __forceinline__ float bfbits2f(ushort_t u) {
    return __uint_as_float(((unsigned int)u) << 16);
}
__device__ __forceinline__ ushort_t f2bf(float f) {
    unsigned int x = __float_as_uint(f);
    unsigned int lsb = (x >> 16) & 1u;
    x += 0x7fffu + lsb;
    return (ushort_t)(x >> 16);
}

// fp32 -> (hi, lo) bf16 pair, processing 4 floats/thread
__global__ __launch_bounds__(256)
void conv_hilo(const float* __restrict__ in, ushort_t* __restrict__ hi,
               ushort_t* __restrict__ lo, int n4)
{
    int i = blockIdx.x * 256 + threadIdx.x;
    if (i >= n4) return;
    float4 x = ((const float4*)in)[i];
    ushort4 h, l;
    h.x = f2bf(x.x); l.x = f2bf(x.x - bfbits2f(h.x));
    h.y = f2bf(x.y); l.y = f2bf(x.y - bfbits2f(h.y));
    h.z = f2bf(x.z); l.z = f2bf(x.z - bfbits2f(h.z));
    h.w = f2bf(x.w); l.w = f2bf(x.w - bfbits2f(h.w));
    ((ushort4*)hi)[i] = h;
    ((ushort4*)lo)[i] = l;
}

__global__ __launch_bounds__(256)
void bias_cat(const float* __restrict__ bq, const float* __restrict__ bk,
              const float* __restrict__ bv, const float* __restrict__ bp,
              float* __restrict__ bcat)
{
    int i = blockIdx.x * 256 + threadIdx.x;   // 0..2047
    float v;
    if      (i < 512)  v = bq[i];
    else if (i < 1024) v = bk[i - 512];
    else if (i < 1536) v = bv[i - 1024];
    else               v = bp[i - 1536];
    bcat[i] = v;
}

// bf16x2-split MFMA GEMM: C[m,c] = sum_k A[m,k]*W[c,k] + bias[c]
// A: [8192][512] hi/lo bf16. B: [rows][512] hi/lo bf16 (rows = cols of W).
// MODE 0: B rows 0..1535 (Wq|Wk|Wv): scatter bf16 to q/k (split-head) and vt (transposed).
// MODE 1: B rows pre-offset (Wp): fp32 out [m][512].
template<int MODE>
__global__ __launch_bounds__(256)
void mgemm(const ushort_t* __restrict__ Ahi, const ushort_t* __restrict__ Alo,
           const ushort_t* __restrict__ Bhi, const ushort_t* __restrict__ Blo,
           const float* __restrict__ bias,
           ushort_t* __restrict__ q_o, ushort_t* __restrict__ k_o,
           ushort_t* __restrict__ vt_o, float* __restrict__ p_o)
{
    __shared__ __align__(16) ushort_t As[2][128][40];
    __shared__ __align__(16) ushort_t Bs[2][128][40];

    const int t     = threadIdx.x;
    const int wid   = t >> 6;
    const int lane  = t & 63;
    const int lan16 = lane & 15;
    const int quad  = lane >> 4;
    const int wm    = (wid & 1) * 64;
    const int wn    = (wid >> 1) * 64;

    const int col0 = blockIdx.x * 128;
    const int row0 = blockIdx.y * 128;

    const int srow = t >> 1;          // 0..127
    const int skof = (t & 1) * 16;    // 0 or 16

    float4_t acc[4][4];
    #pragma unroll
    for (int i = 0; i < 4; i++)
        #pragma unroll
        for (int j = 0; j < 4; j++) acc[i][j] = (float4_t){0.f, 0.f, 0.f, 0.f};

    for (int k0 = 0; k0 < DM; k0 += 32) {
        const size_t aoff = (size_t)(row0 + srow) * DM + k0 + skof;
        const size_t boff = (size_t)(col0 + srow) * DM + k0 + skof;
        uint4 ah0 = *(const uint4*)(Ahi + aoff);
        uint4 ah1 = *(const uint4*)(Ahi + aoff + 8);
        uint4 al0 = *(const uint4*)(Alo + aoff);
        uint4 al1 = *(const uint4*)(Alo + aoff + 8);
        uint4 bh0 = *(const uint4*)(Bhi + boff);
        uint4 bh1 = *(const uint4*)(Bhi + boff + 8);
        uint4 bl0 = *(const uint4*)(Blo + boff);
        uint4 bl1 = *(const uint4*)(Blo + boff + 8);
        __syncthreads();   // prev-iter readers done
        *(uint4*)&As[0][srow][skof]     = ah0;
        *(uint4*)&As[0][srow][skof + 8] = ah1;
        *(uint4*)&As[1][srow][skof]     = al0;
        *(uint4*)&As[1][srow][skof + 8] = al1;
        *(uint4*)&Bs[0][srow][skof]     = bh0;
        *(uint4*)&Bs[0][srow][skof + 8] = bh1;
        *(uint4*)&Bs[1][srow][skof]     = bl0;
        *(uint4*)&Bs[1][srow][skof + 8] = bl1;
        __syncthreads();

        short8_t afh[4], afl[4], bfh[4], bfl[4];
        #pragma unroll
        for (int i = 0; i < 4; i++) {
            afh[i] = *(const short8_t*)&As[0][wm + i * 16 + lan16][quad * 8];
            afl[i] = *(const short8_t*)&As[1][wm + i * 16 + lan16][quad * 8];
            bfh[i] = *(const short8_t*)&Bs[0][wn + i * 16 + lan16][quad * 8];
            bfl[i] = *(const short8_t*)&Bs[1][wn + i * 16 + lan16][quad * 8];
        }
        #pragma unroll
        for (int i = 0; i < 4; i++)
            #pragma unroll
            for (int j = 0; j < 4; j++) {
                float4_t a = acc[i][j];
                a = __builtin_amdgcn_mfma_f32_16x16x32_bf16(afh[i], bfh[j], a, 0, 0, 0);
                a = __builtin_amdgcn_mfma_f32_16x16x32_bf16(afh[i], bfl[j], a, 0, 0, 0);
                a = __builtin_amdgcn_mfma_f32_16x16x32_bf16(afl[i], bfh[j], a, 0, 0, 0);
                acc[i][j] = a;
            }
    }

    // epilogue: C row = row0+wm+i*16+quad*4+reg, col = col0+wn+j*16+lan16
    #pragma unroll
    for (int j = 0; j < 4; j++) {
        int col = col0 + wn + j * 16 + lan16;
        float bv = bias[col];
        #pragma unroll
        for (int i = 0; i < 4; i++) {
            #pragma unroll
            for (int reg = 0; reg < 4; reg++) {
                int row = row0 + wm + i * 16 + quad * 4 + reg;
                float v = acc[i][j][reg] + bv;
                if (MODE == 0) {
                    int w = col >> 9;        // 0=q 1=k 2=v (block-uniform)
                    int c = col & 511;
                    int hh = c & 7, dh = c >> 3;
                    int n = row >> 11, s = row & 2047;
                    if (w == 0)
                        q_o[(((size_t)(n * H_N + hh)) * SEQ + s) * DH + dh] = f2bf(v);
                    else if (w == 1)
                        k_o[(((size_t)(n * H_N + hh)) * SEQ + s) * DH + dh] = f2bf(v);
                    else
                        vt_o[(((size_t)(n * H_N + hh)) * DH + dh) * SEQ + s] = f2bf(v);
                } else {
                    p_o[(size_t)row * DM + col] = v;
                }
            }
        }
    }
}

// MFMA flash attention. Block = (n, h, 64 q-rows); 4 waves, wave owns 16 q-rows.
// q,k: bf16 [n,h,s,64]; vt: bf16 [n,h,64,s]; ctx out -> hi/lo bf16 [n,s,512].
__global__ __launch_bounds__(256)
void attn_k(const ushort_t* __restrict__ qw, const ushort_t* __restrict__ kw,
            const ushort_t* __restrict__ vt, const float* __restrict__ lsc,
            const float* __restrict__ rpe,
            ushort_t* __restrict__ ctxhi, ushort_t* __restrict__ ctxlo)
{
    __shared__ __align__(16) ushort_t K_s[64][72];
    __shared__ __align__(16) ushort_t VT_s[64][72];
    __shared__ __align__(16) ushort_t P_s[4][16][80];
    __shared__ float bias_s[128];

    const int t     = threadIdx.x;
    const int wid   = t >> 6;
    const int lane  = t & 63;
    const int lan16 = lane & 15;
    const int quad  = lane >> 4;

    const int qt = blockIdx.x;
    const int h  = blockIdx.y;
    const int n  = blockIdx.z;
    const int q0 = qt * 64;

    const size_t headoff = ((size_t)(n * H_N + h)) * SEQ * DH;
    const ushort_t* qh  = qw + headoff;
    const ushort_t* kh  = kw + headoff;
    const ushort_t* vth = vt + headoff;

    float ls = lsc[h];
    const float lm = 4.60517018598809136804f;   // log(100)
    if (ls > lm) ls = lm;
    const float scale = __expf(ls) * 0.04419417382415921757f;  // 1/sqrt(512)

    short8_t qa0, qa1;
    {
        const ushort_t* src = qh + (size_t)(q0 + wid * 16 + lan16) * DH + quad * 8;
        qa0 = *(const short8_t*)(src);
        qa1 = *(const short8_t*)(src + 32);
    }

    float m_run[4], l_run[4];
    #pragma unroll
    for (int r = 0; r < 4; r++) { m_run[r] = -1e30f; l_run[r] = 0.f; }
    float4_t o[4];
    #pragma unroll
    for (int s = 0; s < 4; s++) o[s] = (float4_t){0.f, 0.f, 0.f, 0.f};

    const int key_st = t >> 2;
    const int part   = t & 3;

    for (int j0 = 0; j0 < SEQ; j0 += 64) {
        __syncthreads();
        {
            const ushort_t* ksrc = kh + (size_t)(j0 + key_st) * DH + part * 16;
            *(uint4*)&K_s[key_st][part * 16]     = *(const uint4*)(ksrc);
            *(uint4*)&K_s[key_st][part * 16 + 8] = *(const uint4*)(ksrc + 8);
            const ushort_t* vsrc = vth + (size_t)key_st * SEQ + j0 + part * 16;
            *(uint4*)&VT_s[key_st][part * 16]     = *(const uint4*)(vsrc);
            *(uint4*)&VT_s[key_st][part * 16 + 8] = *(const uint4*)(vsrc + 8);
        }
        if (t < 127) {
            int idx = q0 - j0 + 1984 + t;
            float x = rpe[idx * H_N + h];
            bias_s[t] = 1.0f / (1.0f + __expf(-x));
        }
        __syncthreads();

        float4_t sc[4];
        #pragma unroll
        for (int sub = 0; sub < 4; sub++) {
            const ushort_t* kb = &K_s[sub * 16 + lan16][quad * 8];
            short8_t kb0 = *(const short8_t*)(kb);
            short8_t kb1 = *(const short8_t*)(kb + 32);
            float4_t a = (float4_t){0.f, 0.f, 0.f, 0.f};
            a = __builtin_amdgcn_mfma_f32_16x16x32_bf16(qa0, kb0, a, 0, 0, 0);
            a = __builtin_amdgcn_mfma_f32_16x16x32_bf16(qa1, kb1, a, 0, 0, 0);
            sc[sub] = a;
        }

        float sval[4][4];
        float mx[4] = {-1e30f, -1e30f, -1e30f, -1e30f};
        const int rbase = quad * 4;
        #pragma unroll
        for (int sub = 0; sub < 4; sub++) {
            int cl = sub * 16 + lan16;
            #pragma unroll
            for (int reg = 0; reg < 4; reg++) {
                int rl = wid * 16 + rbase + reg;
                float v = sc[sub][reg] * scale + bias_s[rl - cl + 63];
                sval[sub][reg] = v;
                mx[reg] = fmaxf(mx[reg], v);
            }
        }
        #pragma unroll
        for (int off = 1; off < 16; off <<= 1) {
            #pragma unroll
            for (int reg = 0; reg < 4; reg++)
                mx[reg] = fmaxf(mx[reg], __shfl_xor(mx[reg], off));
        }
        float alpha[4], ps[4];
        #pragma unroll
        for (int reg = 0; reg < 4; reg++) {
            float mnew = fmaxf(m_run[reg], mx[reg]);
            alpha[reg] = __expf(m_run[reg] - mnew);
            m_run[reg] = mnew;
            ps[reg] = 0.f;
        }
        #pragma unroll
        for (int sub = 0; sub < 4; sub++)
            #pragma unroll
            for (int reg = 0; reg < 4; reg++) {
                float p = __expf(sval[sub][reg] - m_run[reg]);
                sval[sub][reg] = p;
                ps[reg] += p;
            }
        #pragma unroll
        for (int off = 1; off < 16; off <<= 1) {
            #pragma unroll
            for (int reg = 0; reg < 4; reg++)
                ps[reg] += __shfl_xor(ps[reg], off);
        }
        #pragma unroll
        for (int reg = 0; reg < 4; reg++)
            l_run[reg] = l_run[reg] * alpha[reg] + ps[reg];

        #pragma unroll
        for (int sub = 0; sub < 4; sub++)
            #pragma unroll
            for (int reg = 0; reg < 4; reg++)
                P_s[wid][rbase + reg][sub * 16 + lan16] = f2bf(sval[sub][reg]);
        __syncthreads();

        short8_t pa0, pa1;
        {
            const ushort_t* pp = &P_s[wid][lan16][quad * 8];
            pa0 = *(const short8_t*)(pp);
            pa1 = *(const short8_t*)(pp + 32);
        }
        #pragma unroll
        for (int sub = 0; sub < 4; sub++) {
            const ushort_t* vb = &VT_s[sub * 16 + lan16][quad * 8];
            short8_t vb0 = *(const short8_t*)(vb);
            short8_t vb1 = *(const short8_t*)(vb + 32);
            float4_t a = o[sub];
            #pragma unroll
            for (int reg = 0; reg < 4; reg++) a[reg] *= alpha[reg];
            a = __builtin_amdgcn_mfma_f32_16x16x32_bf16(pa0, vb0, a, 0, 0, 0);
            a = __builtin_amdgcn_mfma_f32_16x16x32_bf16(pa1, vb1, a, 0, 0, 0);
            o[sub] = a;
        }
    }

    float inv[4];
    #pragma unroll
    for (int reg = 0; reg < 4; reg++) inv[reg] = 1.0f / l_run[reg];
    #pragma unroll
    for (int sub = 0; sub < 4; sub++) {
        #pragma unroll
        for (int reg = 0; reg < 4; reg++) {
            int row = q0 + wid * 16 + quad * 4 + reg;
            float v = o[sub][reg] * inv[reg];
            size_t idx = ((size_t)n * SEQ + row) * DM + h * DH + sub * 16 + lan16;
            ushort_t hi = f2bf(v);
            ctxhi[idx] = hi;
            ctxlo[idx] = f2bf(v - bfbits2f(hi));
        }
    }
}

extern "C" void kernel_launch(void* const* d_in, const int* in_sizes, int n_in,
                              void* d_out, int out_size, void* d_ws, size_t ws_size,
                              hipStream_t stream) {
    const float* query = (const float*)d_in[0];
    const float* Wq  = (const float*)d_in[1];
    const float* bq  = (const float*)d_in[2];
    const float* Wk  = (const float*)d_in[3];
    const float* bk  = (const float*)d_in[4];
    const float* Wv  = (const float*)d_in[5];
    const float* bv  = (const float*)d_in[6];
    const float* Wp  = (const float*)d_in[7];
    const float* bp  = (const float*)d_in[8];
    const float* lsc = (const float*)d_in[9];
    const float* rpe = (const float*)d_in[10];

    const size_t QEL = (size_t)N_B * SEQ * DM;     // 4,194,304
    const size_t WEL = (size_t)DM * DM;            // 262,144
    char* ws = (char*)d_ws;
    ushort_t* qhi  = (ushort_t*)(ws);
    ushort_t* qlo  = qhi + QEL;
    ushort_t* w4hi = qlo + QEL;                    // 4*WEL: Wq|Wk|Wv|Wp
    ushort_t* w4lo = w4hi + 4 * WEL;
    float*    bcat = (float*)(w4lo + 4 * WEL);     // 2048 floats
    ushort_t* qb   = (ushort_t*)(bcat + 2048);
    ushort_t* kb   = qb + QEL;
    ushort_t* vtb  = kb + QEL;
    ushort_t* chi  = vtb + QEL;
    ushort_t* clo  = chi + QEL;

    conv_hilo<<<QEL / 4 / 256, 256, 0, stream>>>(query, qhi, qlo, QEL / 4);
    conv_hilo<<<WEL / 4 / 256, 256, 0, stream>>>(Wq, w4hi,           w4lo,           WEL / 4);
    conv_hilo<<<WEL / 4 / 256, 256, 0, stream>>>(Wk, w4hi + WEL,     w4lo + WEL,     WEL / 4);
    conv_hilo<<<WEL / 4 / 256, 256, 0, stream>>>(Wv, w4hi + 2 * WEL, w4lo + 2 * WEL, WEL / 4);
    conv_hilo<<<WEL / 4 / 256, 256, 0, stream>>>(Wp, w4hi + 3 * WEL, w4lo + 3 * WEL, WEL / 4);
    bias_cat<<<8, 256, 0, stream>>>(bq, bk, bv, bp, bcat);

    dim3 g1(1536 / 128, (N_B * SEQ) / 128);        // (12, 64)
    mgemm<0><<<g1, 256, 0, stream>>>(qhi, qlo, w4hi, w4lo, bcat, qb, kb, vtb, nullptr);

    dim3 ga(SEQ / 64, H_N, N_B);                   // (32, 8, 4)
    attn_k<<<ga, 256, 0, stream>>>(qb, kb, vtb, lsc, rpe, chi, clo);

    dim3 g2(DM / 128, (N_B * SEQ) / 128);          // (4, 64)
    mgemm<1><<<g2, 256, 0, stream>>>(chi, clo, w4hi + 3 * WEL, w4lo + 3 * WEL,
                                     bcat + 1536, nullptr, nullptr, nullptr, (float*)d_out);
}

// Round 8
// 276.656 us; speedup vs baseline: 3.6175x; 1.1663x over previous
//
#include <hip/hip_runtime.h>
#include <math.h>

#define N_B 4
#define SEQ 2048
#define DM  512
#define H_N 8
#define DH  64

typedef unsigned short ushort_t;
typedef __attribute__((ext_vector_type(8))) short short8_t;
typedef __attribute__((ext_vector_type(4))) float float4_t;

#define LOG2E 1.4426950408889634074f

__device__ __forceinline__ float bfbits2f(ushort_t u) {
    return __uint_as_float(((unsigned int)u) << 16);
}
__device__ __forceinline__ ushort_t f2bf(float f) {
    unsigned int x = __float_as_uint(f);
    unsigned int lsb = (x >> 16) & 1u;
    x += 0x7fffu + lsb;
    return (ushort_t)(x >> 16);
}
__device__ __forceinline__ unsigned int pack2bf(float a, float b) {
    return ((unsigned int)f2bf(b) << 16) | (unsigned int)f2bf(a);
}
__device__ __forceinline__ float fexp2(float x) {
#if __has_builtin(__builtin_amdgcn_exp2f)
    return __builtin_amdgcn_exp2f(x);
#else
    return exp2f(x);
#endif
}

// Merged pre-pass: query + 4 weights -> hi/lo bf16; bias concat.
#define Q4 1048576   // query float4 groups
#define W4 65536     // per-weight float4 groups
__global__ __launch_bounds__(256)
void prep(const float* __restrict__ query,
          const float* __restrict__ Wq, const float* __restrict__ Wk,
          const float* __restrict__ Wv, const float* __restrict__ Wp,
          const float* __restrict__ bq, const float* __restrict__ bk,
          const float* __restrict__ bv, const float* __restrict__ bp,
          ushort_t* __restrict__ qhi, ushort_t* __restrict__ qlo,
          ushort_t* __restrict__ whi, ushort_t* __restrict__ wlo,
          float* __restrict__ bcat)
{
    int i = blockIdx.x * 256 + threadIdx.x;
    if (i < Q4) {
        float4 x = ((const float4*)query)[i];
        ushort4 h, l;
        h.x = f2bf(x.x); l.x = f2bf(x.x - bfbits2f(h.x));
        h.y = f2bf(x.y); l.y = f2bf(x.y - bfbits2f(h.y));
        h.z = f2bf(x.z); l.z = f2bf(x.z - bfbits2f(h.z));
        h.w = f2bf(x.w); l.w = f2bf(x.w - bfbits2f(h.w));
        ((ushort4*)qhi)[i] = h;
        ((ushort4*)qlo)[i] = l;
    } else if (i < Q4 + 4 * W4) {
        int wi = i - Q4;
        int w = wi >> 16;
        const float* W = (w == 0) ? Wq : (w == 1) ? Wk : (w == 2) ? Wv : Wp;
        float4 x = ((const float4*)W)[wi & (W4 - 1)];
        ushort4 h, l;
        h.x = f2bf(x.x); l.x = f2bf(x.x - bfbits2f(h.x));
        h.y = f2bf(x.y); l.y = f2bf(x.y - bfbits2f(h.y));
        h.z = f2bf(x.z); l.z = f2bf(x.z - bfbits2f(h.z));
        h.w = f2bf(x.w); l.w = f2bf(x.w - bfbits2f(h.w));
        ((ushort4*)whi)[wi] = h;
        ((ushort4*)wlo)[wi] = l;
    } else {
        int bi = i - (Q4 + 4 * W4);
        if (bi < 512) {
            int seg = bi >> 7;           // 128 float4 groups per 512-float segment
            int off = bi & 127;
            const float* B = (seg == 0) ? bq : (seg == 1) ? bk : (seg == 2) ? bv : bp;
            ((float4*)bcat)[bi] = ((const float4*)B)[off];
        }
    }
}

// bf16x2-split MFMA GEMM: C[m,c] = sum_k A[m,k]*W[c,k] + bias[c]
// MODE 0: B rows 0..1535 (Wq|Wk|Wv): scatter bf16 to q/k (split-head) and vt (transposed).
// MODE 1: fp32 out [m][512].
template<int MODE>
__global__ __launch_bounds__(256)
void mgemm(const ushort_t* __restrict__ Ahi, const ushort_t* __restrict__ Alo,
           const ushort_t* __restrict__ Bhi, const ushort_t* __restrict__ Blo,
           const float* __restrict__ bias,
           ushort_t* __restrict__ q_o, ushort_t* __restrict__ k_o,
           ushort_t* __restrict__ vt_o, float* __restrict__ p_o)
{
    __shared__ __align__(16) ushort_t As[2][128][40];
    __shared__ __align__(16) ushort_t Bs[2][128][40];

    const int t     = threadIdx.x;
    const int wid   = t >> 6;
    const int lane  = t & 63;
    const int lan16 = lane & 15;
    const int quad  = lane >> 4;
    const int wm    = (wid & 1) * 64;
    const int wn    = (wid >> 1) * 64;

    const int col0 = blockIdx.x * 128;
    const int row0 = blockIdx.y * 128;

    const int srow = t >> 1;
    const int skof = (t & 1) * 16;

    float4_t acc[4][4];
    #pragma unroll
    for (int i = 0; i < 4; i++)
        #pragma unroll
        for (int j = 0; j < 4; j++) acc[i][j] = (float4_t){0.f, 0.f, 0.f, 0.f};

    for (int k0 = 0; k0 < DM; k0 += 32) {
        const size_t aoff = (size_t)(row0 + srow) * DM + k0 + skof;
        const size_t boff = (size_t)(col0 + srow) * DM + k0 + skof;
        uint4 ah0 = *(const uint4*)(Ahi + aoff);
        uint4 ah1 = *(const uint4*)(Ahi + aoff + 8);
        uint4 al0 = *(const uint4*)(Alo + aoff);
        uint4 al1 = *(const uint4*)(Alo + aoff + 8);
        uint4 bh0 = *(const uint4*)(Bhi + boff);
        uint4 bh1 = *(const uint4*)(Bhi + boff + 8);
        uint4 bl0 = *(const uint4*)(Blo + boff);
        uint4 bl1 = *(const uint4*)(Blo + boff + 8);
        __syncthreads();
        *(uint4*)&As[0][srow][skof]     = ah0;
        *(uint4*)&As[0][srow][skof + 8] = ah1;
        *(uint4*)&As[1][srow][skof]     = al0;
        *(uint4*)&As[1][srow][skof + 8] = al1;
        *(uint4*)&Bs[0][srow][skof]     = bh0;
        *(uint4*)&Bs[0][srow][skof + 8] = bh1;
        *(uint4*)&Bs[1][srow][skof]     = bl0;
        *(uint4*)&Bs[1][srow][skof + 8] = bl1;
        __syncthreads();

        short8_t afh[4], afl[4], bfh[4], bfl[4];
        #pragma unroll
        for (int i = 0; i < 4; i++) {
            afh[i] = *(const short8_t*)&As[0][wm + i * 16 + lan16][quad * 8];
            afl[i] = *(const short8_t*)&As[1][wm + i * 16 + lan16][quad * 8];
            bfh[i] = *(const short8_t*)&Bs[0][wn + i * 16 + lan16][quad * 8];
            bfl[i] = *(const short8_t*)&Bs[1][wn + i * 16 + lan16][quad * 8];
        }
        #pragma unroll
        for (int i = 0; i < 4; i++)
            #pragma unroll
            for (int j = 0; j < 4; j++) {
                float4_t a = acc[i][j];
                a = __builtin_amdgcn_mfma_f32_16x16x32_bf16(afh[i], bfh[j], a, 0, 0, 0);
                a = __builtin_amdgcn_mfma_f32_16x16x32_bf16(afh[i], bfl[j], a, 0, 0, 0);
                a = __builtin_amdgcn_mfma_f32_16x16x32_bf16(afl[i], bfh[j], a, 0, 0, 0);
                acc[i][j] = a;
            }
    }

    #pragma unroll
    for (int j = 0; j < 4; j++) {
        int col = col0 + wn + j * 16 + lan16;
        float bv = bias[col];
        #pragma unroll
        for (int i = 0; i < 4; i++) {
            #pragma unroll
            for (int reg = 0; reg < 4; reg++) {
                int row = row0 + wm + i * 16 + quad * 4 + reg;
                float v = acc[i][j][reg] + bv;
                if (MODE == 0) {
                    int w = col >> 9;
                    int c = col & 511;
                    int hh = c & 7, dh = c >> 3;
                    int n = row >> 11, s = row & 2047;
                    if (w == 0)
                        q_o[(((size_t)(n * H_N + hh)) * SEQ + s) * DH + dh] = f2bf(v);
                    else if (w == 1)
                        k_o[(((size_t)(n * H_N + hh)) * SEQ + s) * DH + dh] = f2bf(v);
                    else
                        vt_o[(((size_t)(n * H_N + hh)) * DH + dh) * SEQ + s] = f2bf(v);
                } else {
                    p_o[(size_t)row * DM + col] = v;
                }
            }
        }
    }
}

// MFMA flash attention, S^T orientation.
// Block = (n, h, 128 q-rows); 4 waves, wave owns 32 q-rows (2 B-frags of 16).
// S^T = K·Q^T  (C: col=lan16=qrow, row=quad*4+reg=key)
// O^T = V^T·P^T (C: col=lan16=qrow, row=quad*4+reg=dim)
__global__ __launch_bounds__(256)
void attn_k(const ushort_t* __restrict__ qw, const ushort_t* __restrict__ kw,
            const ushort_t* __restrict__ vt, const float* __restrict__ lsc,
            const float* __restrict__ rpe,
            ushort_t* __restrict__ ctxhi, ushort_t* __restrict__ ctxlo)
{
    __shared__ __align__(16) ushort_t K_s[64][72];        // [key][dim]
    __shared__ __align__(16) ushort_t VT_s[64][72];       // [dim][key]
    __shared__ __align__(16) unsigned int Pp[4][2][16][36]; // [wave][qf][qrow16][key-pair u32]
    __shared__ float bias_s[192];

    const int t     = threadIdx.x;
    const int wid   = t >> 6;
    const int lane  = t & 63;
    const int lan16 = lane & 15;
    const int quad  = lane >> 4;

    const int qt = blockIdx.x;    // 0..15
    const int h  = blockIdx.y;
    const int n  = blockIdx.z;
    const int q0 = qt * 128;

    const size_t headoff = ((size_t)(n * H_N + h)) * SEQ * DH;
    const ushort_t* qh  = qw + headoff;
    const ushort_t* kh  = kw + headoff;
    const ushort_t* vth = vt + headoff;

    float ls = lsc[h];
    const float lm = 4.60517018598809136804f;   // log(100)
    if (ls > lm) ls = lm;
    const float scale2 = __expf(ls) * 0.04419417382415921757f * LOG2E;

    // Q as B-operand: B[k=d][n=qrow]: lane lan16 = qrow, holds d = half*32+quad*8..+7
    short8_t qb[2][2];
    #pragma unroll
    for (int qf = 0; qf < 2; qf++) {
        const ushort_t* src = qh + (size_t)(q0 + wid * 32 + qf * 16 + lan16) * DH + quad * 8;
        qb[qf][0] = *(const short8_t*)(src);
        qb[qf][1] = *(const short8_t*)(src + 32);
    }

    float m_run[2] = {-1e30f, -1e30f};
    float l_run[2] = {0.f, 0.f};
    float4_t o[4][2];   // [dim-sub][qf]
    #pragma unroll
    for (int ds = 0; ds < 4; ds++)
        #pragma unroll
        for (int qf = 0; qf < 2; qf++) o[ds][qf] = (float4_t){0.f, 0.f, 0.f, 0.f};

    const int key_st = t >> 2;
    const int part   = t & 3;

    for (int j0 = 0; j0 < SEQ; j0 += 64) {
        __syncthreads();
        {
            const ushort_t* ksrc = kh + (size_t)(j0 + key_st) * DH + part * 16;
            *(uint4*)&K_s[key_st][part * 16]     = *(const uint4*)(ksrc);
            *(uint4*)&K_s[key_st][part * 16 + 8] = *(const uint4*)(ksrc + 8);
            const ushort_t* vsrc = vth + (size_t)key_st * SEQ + j0 + part * 16;
            *(uint4*)&VT_s[key_st][part * 16]     = *(const uint4*)(vsrc);
            *(uint4*)&VT_s[key_st][part * 16 + 8] = *(const uint4*)(vsrc + 8);
        }
        if (t < 191) {
            // reversed so per-lane bias addresses ascend with reg
            int idx = q0 - j0 + 127 - t + 2047;   // in [0, 4094]
            float x = rpe[idx * H_N + h];
            bias_s[t] = LOG2E / (1.0f + __expf(-x));
        }
        __syncthreads();

        // ---- S^T = K·Q^T : per wave [64 keys x 32 qrows]
        float4_t st[4][2];
        #pragma unroll
        for (int sub = 0; sub < 4; sub++) {
            const ushort_t* kp = &K_s[sub * 16 + lan16][quad * 8];
            short8_t ka0 = *(const short8_t*)(kp);
            short8_t ka1 = *(const short8_t*)(kp + 32);
            #pragma unroll
            for (int qf = 0; qf < 2; qf++) {
                float4_t a = (float4_t){0.f, 0.f, 0.f, 0.f};
                a = __builtin_amdgcn_mfma_f32_16x16x32_bf16(ka0, qb[qf][0], a, 0, 0, 0);
                a = __builtin_amdgcn_mfma_f32_16x16x32_bf16(ka1, qb[qf][1], a, 0, 0, 0);
                st[sub][qf] = a;
            }
        }

        // ---- softmax: lane owns row q0+wid*32+qf*16+lan16; keys = sub*16+quad*4+reg
        #pragma unroll
        for (int qf = 0; qf < 2; qf++) {
            const int ib = 127 - (wid * 32 + qf * 16 + lan16) + quad * 4;
            float sval[4][4];
            float mx = -1e30f;
            #pragma unroll
            for (int sub = 0; sub < 4; sub++)
                #pragma unroll
                for (int reg = 0; reg < 4; reg++) {
                    float v = st[sub][qf][reg] * scale2 + bias_s[ib + sub * 16 + reg];
                    sval[sub][reg] = v;
                    mx = fmaxf(mx, v);
                }
            mx = fmaxf(mx, __shfl_xor(mx, 16));
            mx = fmaxf(mx, __shfl_xor(mx, 32));
            float mnew  = fmaxf(m_run[qf], mx);
            float alpha = fexp2(m_run[qf] - mnew);
            m_run[qf] = mnew;
            float ps = 0.f;
            #pragma unroll
            for (int sub = 0; sub < 4; sub++)
                #pragma unroll
                for (int reg = 0; reg < 4; reg++) {
                    float p = fexp2(sval[sub][reg] - mnew);
                    sval[sub][reg] = p;
                    ps += p;
                }
            ps += __shfl_xor(ps, 16);
            ps += __shfl_xor(ps, 32);
            l_run[qf] = l_run[qf] * alpha + ps;

            // pack P^T (key-pairs) into wave-private LDS: u32 index = key>>1
            #pragma unroll
            for (int sub = 0; sub < 4; sub++) {
                Pp[wid][qf][lan16][sub * 8 + quad * 2]     = pack2bf(sval[sub][0], sval[sub][1]);
                Pp[wid][qf][lan16][sub * 8 + quad * 2 + 1] = pack2bf(sval[sub][2], sval[sub][3]);
            }
            #pragma unroll
            for (int ds = 0; ds < 4; ds++)
                #pragma unroll
                for (int reg = 0; reg < 4; reg++) o[ds][qf][reg] *= alpha;
        }
        asm volatile("s_waitcnt lgkmcnt(0)" ::: "memory");  // wave-private Pp: no barrier needed

        // ---- O^T += V^T·P^T
        #pragma unroll
        for (int ks = 0; ks < 2; ks++) {
            short8_t pb[2];
            #pragma unroll
            for (int qf = 0; qf < 2; qf++)
                pb[qf] = *(const short8_t*)&Pp[wid][qf][lan16][ks * 16 + quad * 4];
            #pragma unroll
            for (int ds = 0; ds < 4; ds++) {
                short8_t va = *(const short8_t*)&VT_s[ds * 16 + lan16][ks * 32 + quad * 8];
                #pragma unroll
                for (int qf = 0; qf < 2; qf++)
                    o[ds][qf] = __builtin_amdgcn_mfma_f32_16x16x32_bf16(va, pb[qf], o[ds][qf], 0, 0, 0);
            }
        }
    }

    // epilogue: O^T col=lan16 → qrow, row=quad*4+reg → dim(ds*16+..); write hi/lo ctx
    #pragma unroll
    for (int qf = 0; qf < 2; qf++) {
        float inv = 1.0f / l_run[qf];
        int row = q0 + wid * 32 + qf * 16 + lan16;
        size_t base = ((size_t)n * SEQ + row) * DM + h * DH;
        #pragma unroll
        for (int ds = 0; ds < 4; ds++) {
            ushort4 h4, l4;
            float v0 = o[ds][qf][0] * inv;
            float v1 = o[ds][qf][1] * inv;
            float v2 = o[ds][qf][2] * inv;
            float v3 = o[ds][qf][3] * inv;
            h4.x = f2bf(v0); l4.x = f2bf(v0 - bfbits2f(h4.x));
            h4.y = f2bf(v1); l4.y = f2bf(v1 - bfbits2f(h4.y));
            h4.z = f2bf(v2); l4.z = f2bf(v2 - bfbits2f(h4.z));
            h4.w = f2bf(v3); l4.w = f2bf(v3 - bfbits2f(h4.w));
            size_t idx = base + ds * 16 + quad * 4;
            *(ushort4*)(ctxhi + idx) = h4;
            *(ushort4*)(ctxlo + idx) = l4;
        }
    }
}

extern "C" void kernel_launch(void* const* d_in, const int* in_sizes, int n_in,
                              void* d_out, int out_size, void* d_ws, size_t ws_size,
                              hipStream_t stream) {
    const float* query = (const float*)d_in[0];
    const float* Wq  = (const float*)d_in[1];
    const float* bq  = (const float*)d_in[2];
    const float* Wk  = (const float*)d_in[3];
    const float* bk  = (const float*)d_in[4];
    const float* Wv  = (const float*)d_in[5];
    const float* bv  = (const float*)d_in[6];
    const float* Wp  = (const float*)d_in[7];
    const float* bp  = (const float*)d_in[8];
    const float* lsc = (const float*)d_in[9];
    const float* rpe = (const float*)d_in[10];

    const size_t QEL = (size_t)N_B * SEQ * DM;     // 4,194,304
    const size_t WEL = (size_t)DM * DM;            // 262,144
    char* ws = (char*)d_ws;
    ushort_t* qhi  = (ushort_t*)(ws);
    ushort_t* qlo  = qhi + QEL;
    ushort_t* w4hi = qlo + QEL;                    // Wq|Wk|Wv|Wp
    ushort_t* w4lo = w4hi + 4 * WEL;
    float*    bcat = (float*)(w4lo + 4 * WEL);     // 2048 floats
    ushort_t* qb   = (ushort_t*)(bcat + 2048);
    ushort_t* kb   = qb + QEL;
    ushort_t* vtb  = kb + QEL;
    ushort_t* chi  = vtb + QEL;
    ushort_t* clo  = chi + QEL;

    // prep: (Q4 + 4*W4 + 512) threads = 1,311,744 -> 5124 blocks
    prep<<<(Q4 + 4 * W4 + 512 + 255) / 256, 256, 0, stream>>>(
        query, Wq, Wk, Wv, Wp, bq, bk, bv, bp, qhi, qlo, w4hi, w4lo, bcat);

    dim3 g1(1536 / 128, (N_B * SEQ) / 128);        // (12, 64)
    mgemm<0><<<g1, 256, 0, stream>>>(qhi, qlo, w4hi, w4lo, bcat, qb, kb, vtb, nullptr);

    dim3 ga(SEQ / 128, H_N, N_B);                  // (16, 8, 4)
    attn_k<<<ga, 256, 0, stream>>>(qb, kb, vtb, lsc, rpe, chi, clo);

    dim3 g2(DM / 128, (N_B * SEQ) / 128);          // (4, 64)
    mgemm<1><<<g2, 256, 0, stream>>>(chi, clo, w4hi + 3 * WEL, w4lo + 3 * WEL,
                                     bcat + 1536, nullptr, nullptr, nullptr, (float*)d_out);
}

// Round 9
// 267.075 us; speedup vs baseline: 3.7472x; 1.0359x over previous
//
#include <hip/hip_runtime.h>
#include <math.h>

#define N_B 4
#define SEQ 2048
#define DM  512
#define H_N 8
#define DH  64

typedef unsigned short ushort_t;
typedef __attribute__((ext_vector_type(8))) short short8_t;
typedef __attribute__((ext_vector_type(4))) float float4_t;

#define LOG2E 1.4426950408889634074f

__device__ __forceinline__ float bfbits2f(ushort_t u) {
    return __uint_as_float(((unsigned int)u) << 16);
}
__device__ __forceinline__ ushort_t f2bf(float f) {
    unsigned int x = __float_as_uint(f);
    unsigned int lsb = (x >> 16) & 1u;
    x += 0x7fffu + lsb;
    return (ushort_t)(x >> 16);
}
__device__ __forceinline__ unsigned int cvtpk_bf16(float a, float b) {
    unsigned int r;
    asm("v_cvt_pk_bf16_f32 %0, %1, %2" : "=v"(r) : "v"(a), "v"(b));
    return r;   // lo = bf16(a), hi = bf16(b), RNE
}
__device__ __forceinline__ float fexp2(float x) {
#if __has_builtin(__builtin_amdgcn_exp2f)
    return __builtin_amdgcn_exp2f(x);
#else
    return exp2f(x);
#endif
}

// Merged pre-pass: query + 4 weights -> hi/lo bf16; bias concat.
#define Q4 1048576   // query float4 groups
#define W4 65536     // per-weight float4 groups
__global__ __launch_bounds__(256)
void prep(const float* __restrict__ query,
          const float* __restrict__ Wq, const float* __restrict__ Wk,
          const float* __restrict__ Wv, const float* __restrict__ Wp,
          const float* __restrict__ bq, const float* __restrict__ bk,
          const float* __restrict__ bv, const float* __restrict__ bp,
          ushort_t* __restrict__ qhi, ushort_t* __restrict__ qlo,
          ushort_t* __restrict__ whi, ushort_t* __restrict__ wlo,
          float* __restrict__ bcat)
{
    int i = blockIdx.x * 256 + threadIdx.x;
    if (i < Q4) {
        float4 x = ((const float4*)query)[i];
        ushort4 h, l;
        h.x = f2bf(x.x); l.x = f2bf(x.x - bfbits2f(h.x));
        h.y = f2bf(x.y); l.y = f2bf(x.y - bfbits2f(h.y));
        h.z = f2bf(x.z); l.z = f2bf(x.z - bfbits2f(h.z));
        h.w = f2bf(x.w); l.w = f2bf(x.w - bfbits2f(h.w));
        ((ushort4*)qhi)[i] = h;
        ((ushort4*)qlo)[i] = l;
    } else if (i < Q4 + 4 * W4) {
        int wi = i - Q4;
        int w = wi >> 16;
        const float* W = (w == 0) ? Wq : (w == 1) ? Wk : (w == 2) ? Wv : Wp;
        float4 x = ((const float4*)W)[wi & (W4 - 1)];
        ushort4 h, l;
        h.x = f2bf(x.x); l.x = f2bf(x.x - bfbits2f(h.x));
        h.y = f2bf(x.y); l.y = f2bf(x.y - bfbits2f(h.y));
        h.z = f2bf(x.z); l.z = f2bf(x.z - bfbits2f(h.z));
        h.w = f2bf(x.w); l.w = f2bf(x.w - bfbits2f(h.w));
        ((ushort4*)whi)[wi] = h;
        ((ushort4*)wlo)[wi] = l;
    } else {
        int bi = i - (Q4 + 4 * W4);
        if (bi < 512) {
            int seg = bi >> 7;
            int off = bi & 127;
            const float* B = (seg == 0) ? bq : (seg == 1) ? bk : (seg == 2) ? bv : bp;
            ((float4*)bcat)[bi] = ((const float4*)B)[off];
        }
    }
}

// bf16x2-split MFMA GEMM: C[m,c] = sum_k A[m,k]*W[c,k] + bias[c]
// MODE 0: B rows 0..1535 (Wq|Wk|Wv): scatter bf16 to q/k (split-head) and vt (transposed).
// MODE 1: fp32 out [m][512].
template<int MODE>
__global__ __launch_bounds__(256)
void mgemm(const ushort_t* __restrict__ Ahi, const ushort_t* __restrict__ Alo,
           const ushort_t* __restrict__ Bhi, const ushort_t* __restrict__ Blo,
           const float* __restrict__ bias,
           ushort_t* __restrict__ q_o, ushort_t* __restrict__ k_o,
           ushort_t* __restrict__ vt_o, float* __restrict__ p_o)
{
    __shared__ __align__(16) ushort_t As[2][128][40];
    __shared__ __align__(16) ushort_t Bs[2][128][40];

    const int t     = threadIdx.x;
    const int wid   = t >> 6;
    const int lane  = t & 63;
    const int lan16 = lane & 15;
    const int quad  = lane >> 4;
    const int wm    = (wid & 1) * 64;
    const int wn    = (wid >> 1) * 64;

    const int col0 = blockIdx.x * 128;
    const int row0 = blockIdx.y * 128;

    const int srow = t >> 1;
    const int skof = (t & 1) * 16;

    float4_t acc[4][4];
    #pragma unroll
    for (int i = 0; i < 4; i++)
        #pragma unroll
        for (int j = 0; j < 4; j++) acc[i][j] = (float4_t){0.f, 0.f, 0.f, 0.f};

    for (int k0 = 0; k0 < DM; k0 += 32) {
        const size_t aoff = (size_t)(row0 + srow) * DM + k0 + skof;
        const size_t boff = (size_t)(col0 + srow) * DM + k0 + skof;
        uint4 ah0 = *(const uint4*)(Ahi + aoff);
        uint4 ah1 = *(const uint4*)(Ahi + aoff + 8);
        uint4 al0 = *(const uint4*)(Alo + aoff);
        uint4 al1 = *(const uint4*)(Alo + aoff + 8);
        uint4 bh0 = *(const uint4*)(Bhi + boff);
        uint4 bh1 = *(const uint4*)(Bhi + boff + 8);
        uint4 bl0 = *(const uint4*)(Blo + boff);
        uint4 bl1 = *(const uint4*)(Blo + boff + 8);
        __syncthreads();
        *(uint4*)&As[0][srow][skof]     = ah0;
        *(uint4*)&As[0][srow][skof + 8] = ah1;
        *(uint4*)&As[1][srow][skof]     = al0;
        *(uint4*)&As[1][srow][skof + 8] = al1;
        *(uint4*)&Bs[0][srow][skof]     = bh0;
        *(uint4*)&Bs[0][srow][skof + 8] = bh1;
        *(uint4*)&Bs[1][srow][skof]     = bl0;
        *(uint4*)&Bs[1][srow][skof + 8] = bl1;
        __syncthreads();

        short8_t afh[4], afl[4], bfh[4], bfl[4];
        #pragma unroll
        for (int i = 0; i < 4; i++) {
            afh[i] = *(const short8_t*)&As[0][wm + i * 16 + lan16][quad * 8];
            afl[i] = *(const short8_t*)&As[1][wm + i * 16 + lan16][quad * 8];
            bfh[i] = *(const short8_t*)&Bs[0][wn + i * 16 + lan16][quad * 8];
            bfl[i] = *(const short8_t*)&Bs[1][wn + i * 16 + lan16][quad * 8];
        }
        #pragma unroll
        for (int i = 0; i < 4; i++)
            #pragma unroll
            for (int j = 0; j < 4; j++) {
                float4_t a = acc[i][j];
                a = __builtin_amdgcn_mfma_f32_16x16x32_bf16(afh[i], bfh[j], a, 0, 0, 0);
                a = __builtin_amdgcn_mfma_f32_16x16x32_bf16(afh[i], bfl[j], a, 0, 0, 0);
                a = __builtin_amdgcn_mfma_f32_16x16x32_bf16(afl[i], bfh[j], a, 0, 0, 0);
                acc[i][j] = a;
            }
    }

    #pragma unroll
    for (int j = 0; j < 4; j++) {
        int col = col0 + wn + j * 16 + lan16;
        float bv = bias[col];
        #pragma unroll
        for (int i = 0; i < 4; i++) {
            #pragma unroll
            for (int reg = 0; reg < 4; reg++) {
                int row = row0 + wm + i * 16 + quad * 4 + reg;
                float v = acc[i][j][reg] + bv;
                if (MODE == 0) {
                    int w = col >> 9;
                    int c = col & 511;
                    int hh = c & 7, dh = c >> 3;
                    int n = row >> 11, s = row & 2047;
                    if (w == 0)
                        q_o[(((size_t)(n * H_N + hh)) * SEQ + s) * DH + dh] = f2bf(v);
                    else if (w == 1)
                        k_o[(((size_t)(n * H_N + hh)) * SEQ + s) * DH + dh] = f2bf(v);
                    else
                        vt_o[(((size_t)(n * H_N + hh)) * DH + dh) * SEQ + s] = f2bf(v);
                } else {
                    p_o[(size_t)row * DM + col] = v;
                }
            }
        }
    }
}

// MFMA flash attention, S^T orientation, no-max softmax (scores provably bounded).
// Block = (n, h, 128 q-rows); 4 waves, wave owns 32 q-rows (2 B-frags of 16).
// S^T = K·Q^T  (C: col=lan16=qrow, row=quad*4+reg=key)
// O^T = V^T·P^T (C: col=lan16=qrow, row=quad*4+reg=dim)
__global__ __launch_bounds__(256)
void attn_k(const ushort_t* __restrict__ qw, const ushort_t* __restrict__ kw,
            const ushort_t* __restrict__ vt, const float* __restrict__ lsc,
            const float* __restrict__ rpe,
            ushort_t* __restrict__ ctxhi, ushort_t* __restrict__ ctxlo)
{
    __shared__ __align__(16) ushort_t K_s[64][72];          // [key][dim]
    __shared__ __align__(16) ushort_t VT_s[64][72];         // [dim][key]
    __shared__ __align__(16) unsigned int Pp[4][2][16][36]; // [wave][qf][qrow16][key-pair]
    __shared__ float tbl[2176];                             // sigmoid(rpe)*log2e, reversed

    const int t     = threadIdx.x;
    const int wid   = t >> 6;
    const int lane  = t & 63;
    const int lan16 = lane & 15;
    const int quad  = lane >> 4;

    const int qt = blockIdx.x;    // 0..15
    const int h  = blockIdx.y;
    const int n  = blockIdx.z;
    const int q0 = qt * 128;

    const size_t headoff = ((size_t)(n * H_N + h)) * SEQ * DH;
    const ushort_t* qh  = qw + headoff;
    const ushort_t* kh  = kw + headoff;
    const ushort_t* vth = vt + headoff;

    float ls = lsc[h];
    const float lm = 4.60517018598809136804f;   // log(100)
    if (ls > lm) ls = lm;
    const float scale2 = __expf(ls) * 0.04419417382415921757f * LOG2E;

    // bias table: tbl[w] = log2e * sigmoid(rpe[v]), v = q0 + 2174 - w  (reversed ->
    // per-lane lookup addresses ascend with key). w in [0, 2174].
    for (int w = t; w < 2175; w += 256) {
        int v = q0 + 2174 - w;                 // in [q0, q0+2174] subset of [0, 4094]
        float x = rpe[v * H_N + h];
        tbl[w] = LOG2E / (1.0f + __expf(-x));
    }

    // Q as B-operand: lane lan16 = qrow, holds d = half*32+quad*8..+7
    short8_t qb[2][2];
    #pragma unroll
    for (int qf = 0; qf < 2; qf++) {
        const ushort_t* src = qh + (size_t)(q0 + wid * 32 + qf * 16 + lan16) * DH + quad * 8;
        qb[qf][0] = *(const short8_t*)(src);
        qb[qf][1] = *(const short8_t*)(src + 32);
    }

    float l_run[2] = {0.f, 0.f};
    float4_t o[4][2];   // [dim-sub][qf]
    #pragma unroll
    for (int ds = 0; ds < 4; ds++)
        #pragma unroll
        for (int qf = 0; qf < 2; qf++) o[ds][qf] = (float4_t){0.f, 0.f, 0.f, 0.f};

    const int key_st = t >> 2;
    const int part   = t & 3;

    for (int j0 = 0; j0 < SEQ; j0 += 64) {
        __syncthreads();   // prev-tile readers of K_s/VT_s done (also covers tbl build)
        {
            const ushort_t* ksrc = kh + (size_t)(j0 + key_st) * DH + part * 16;
            *(uint4*)&K_s[key_st][part * 16]     = *(const uint4*)(ksrc);
            *(uint4*)&K_s[key_st][part * 16 + 8] = *(const uint4*)(ksrc + 8);
            const ushort_t* vsrc = vth + (size_t)key_st * SEQ + j0 + part * 16;
            *(uint4*)&VT_s[key_st][part * 16]     = *(const uint4*)(vsrc);
            *(uint4*)&VT_s[key_st][part * 16 + 8] = *(const uint4*)(vsrc + 8);
        }
        __syncthreads();

        // ---- S^T = K·Q^T : per wave [64 keys x 32 qrows]
        float4_t st[4][2];
        #pragma unroll
        for (int sub = 0; sub < 4; sub++) {
            const ushort_t* kp = &K_s[sub * 16 + lan16][quad * 8];
            short8_t ka0 = *(const short8_t*)(kp);
            short8_t ka1 = *(const short8_t*)(kp + 32);
            #pragma unroll
            for (int qf = 0; qf < 2; qf++) {
                float4_t a = (float4_t){0.f, 0.f, 0.f, 0.f};
                a = __builtin_amdgcn_mfma_f32_16x16x32_bf16(ka0, qb[qf][0], a, 0, 0, 0);
                a = __builtin_amdgcn_mfma_f32_16x16x32_bf16(ka1, qb[qf][1], a, 0, 0, 0);
                st[sub][qf] = a;
            }
        }

        // ---- no-max softmax: lane owns row q0+wid*32+qf*16+lan16; keys sub*16+quad*4+reg
        #pragma unroll
        for (int qf = 0; qf < 2; qf++) {
            const int wbase = 127 - (wid * 32 + qf * 16 + lan16) + j0 + quad * 4;
            float ps = 0.f;
            #pragma unroll
            for (int sub = 0; sub < 4; sub++) {
                float e0 = fexp2(st[sub][qf][0] * scale2 + tbl[wbase + sub * 16 + 0]);
                float e1 = fexp2(st[sub][qf][1] * scale2 + tbl[wbase + sub * 16 + 1]);
                float e2 = fexp2(st[sub][qf][2] * scale2 + tbl[wbase + sub * 16 + 2]);
                float e3 = fexp2(st[sub][qf][3] * scale2 + tbl[wbase + sub * 16 + 3]);
                ps += (e0 + e1) + (e2 + e3);
                Pp[wid][qf][lan16][sub * 8 + quad * 2]     = cvtpk_bf16(e0, e1);
                Pp[wid][qf][lan16][sub * 8 + quad * 2 + 1] = cvtpk_bf16(e2, e3);
            }
            l_run[qf] += ps;
        }
        asm volatile("s_waitcnt lgkmcnt(0)" ::: "memory");  // wave-private Pp, no barrier

        // ---- O^T += V^T·P^T
        #pragma unroll
        for (int ks = 0; ks < 2; ks++) {
            short8_t pb[2];
            #pragma unroll
            for (int qf = 0; qf < 2; qf++)
                pb[qf] = *(const short8_t*)&Pp[wid][qf][lan16][ks * 16 + quad * 4];
            #pragma unroll
            for (int ds = 0; ds < 4; ds++) {
                short8_t va = *(const short8_t*)&VT_s[ds * 16 + lan16][ks * 32 + quad * 8];
                #pragma unroll
                for (int qf = 0; qf < 2; qf++)
                    o[ds][qf] = __builtin_amdgcn_mfma_f32_16x16x32_bf16(va, pb[qf], o[ds][qf], 0, 0, 0);
            }
        }
    }

    // epilogue: reduce l across quads; O^T col=lan16=qrow, row=quad*4+reg=dim
    #pragma unroll
    for (int qf = 0; qf < 2; qf++) {
        float l = l_run[qf];
        l += __shfl_xor(l, 16);
        l += __shfl_xor(l, 32);
        float inv = 1.0f / l;
        int row = q0 + wid * 32 + qf * 16 + lan16;
        size_t base = ((size_t)n * SEQ + row) * DM + h * DH;
        #pragma unroll
        for (int ds = 0; ds < 4; ds++) {
            ushort4 h4, l4;
            float v0 = o[ds][qf][0] * inv;
            float v1 = o[ds][qf][1] * inv;
            float v2 = o[ds][qf][2] * inv;
            float v3 = o[ds][qf][3] * inv;
            h4.x = f2bf(v0); l4.x = f2bf(v0 - bfbits2f(h4.x));
            h4.y = f2bf(v1); l4.y = f2bf(v1 - bfbits2f(h4.y));
            h4.z = f2bf(v2); l4.z = f2bf(v2 - bfbits2f(h4.z));
            h4.w = f2bf(v3); l4.w = f2bf(v3 - bfbits2f(h4.w));
            size_t idx = base + ds * 16 + quad * 4;
            *(ushort4*)(ctxhi + idx) = h4;
            *(ushort4*)(ctxlo + idx) = l4;
        }
    }
}

extern "C" void kernel_launch(void* const* d_in, const int* in_sizes, int n_in,
                              void* d_out, int out_size, void* d_ws, size_t ws_size,
                              hipStream_t stream) {
    const float* query = (const float*)d_in[0];
    const float* Wq  = (const float*)d_in[1];
    const float* bq  = (const float*)d_in[2];
    const float* Wk  = (const float*)d_in[3];
    const float* bk  = (const float*)d_in[4];
    const float* Wv  = (const float*)d_in[5];
    const float* bv  = (const float*)d_in[6];
    const float* Wp  = (const float*)d_in[7];
    const float* bp  = (const float*)d_in[8];
    const float* lsc = (const float*)d_in[9];
    const float* rpe = (const float*)d_in[10];

    const size_t QEL = (size_t)N_B * SEQ * DM;     // 4,194,304
    const size_t WEL = (size_t)DM * DM;            // 262,144
    char* ws = (char*)d_ws;
    ushort_t* qhi  = (ushort_t*)(ws);
    ushort_t* qlo  = qhi + QEL;
    ushort_t* w4hi = qlo + QEL;                    // Wq|Wk|Wv|Wp
    ushort_t* w4lo = w4hi + 4 * WEL;
    float*    bcat = (float*)(w4lo + 4 * WEL);     // 2048 floats
    ushort_t* qb   = (ushort_t*)(bcat + 2048);
    ushort_t* kb   = qb + QEL;
    ushort_t* vtb  = kb + QEL;
    ushort_t* chi  = vtb + QEL;
    ushort_t* clo  = chi + QEL;

    prep<<<(Q4 + 4 * W4 + 512 + 255) / 256, 256, 0, stream>>>(
        query, Wq, Wk, Wv, Wp, bq, bk, bv, bp, qhi, qlo, w4hi, w4lo, bcat);

    dim3 g1(1536 / 128, (N_B * SEQ) / 128);        // (12, 64)
    mgemm<0><<<g1, 256, 0, stream>>>(qhi, qlo, w4hi, w4lo, bcat, qb, kb, vtb, nullptr);

    dim3 ga(SEQ / 128, H_N, N_B);                  // (16, 8, 4)
    attn_k<<<ga, 256, 0, stream>>>(qb, kb, vtb, lsc, rpe, chi, clo);

    dim3 g2(DM / 128, (N_B * SEQ) / 128);          // (4, 64)
    mgemm<1><<<g2, 256, 0, stream>>>(chi, clo, w4hi + 3 * WEL, w4lo + 3 * WEL,
                                     bcat + 1536, nullptr, nullptr, nullptr, (float*)d_out);
}

// Round 10
// 232.215 us; speedup vs baseline: 4.3098x; 1.1501x over previous
//
#include <hip/hip_runtime.h>
#include <math.h>

#define N_B 4
#define SEQ 2048
#define DM  512
#define H_N 8
#define DH  64

typedef unsigned short ushort_t;
typedef __attribute__((ext_vector_type(8))) short short8_t;
typedef __attribute__((ext_vector_type(4))) float float4_t;

#define LOG2E 1.4426950408889634074f

__device__ __forceinline__ ushort_t f2bf(float f) {
    unsigned int x = __float_as_uint(f);
    unsigned int lsb = (x >> 16) & 1u;
    x += 0x7fffu + lsb;
    return (ushort_t)(x >> 16);
}
__device__ __forceinline__ unsigned int cvtpk_bf16(float a, float b) {
    unsigned int r;
    asm("v_cvt_pk_bf16_f32 %0, %1, %2" : "=v"(r) : "v"(a), "v"(b));
    return r;   // lo = bf16(a), hi = bf16(b), RNE
}
__device__ __forceinline__ float fexp2(float x) {
#if __has_builtin(__builtin_amdgcn_exp2f)
    return __builtin_amdgcn_exp2f(x);
#else
    return exp2f(x);
#endif
}

// Merged pre-pass: query + 4 weights -> bf16 (RNE); bias concat.
#define Q4 1048576   // query float4 groups
#define W4 65536     // per-weight float4 groups
__global__ __launch_bounds__(256)
void prep(const float* __restrict__ query,
          const float* __restrict__ Wq, const float* __restrict__ Wk,
          const float* __restrict__ Wv, const float* __restrict__ Wp,
          const float* __restrict__ bq, const float* __restrict__ bk,
          const float* __restrict__ bv, const float* __restrict__ bp,
          ushort_t* __restrict__ q16, ushort_t* __restrict__ w16,
          float* __restrict__ bcat)
{
    int i = blockIdx.x * 256 + threadIdx.x;
    if (i < Q4) {
        float4 x = ((const float4*)query)[i];
        uint2 p;
        p.x = cvtpk_bf16(x.x, x.y);
        p.y = cvtpk_bf16(x.z, x.w);
        ((uint2*)q16)[i] = p;
    } else if (i < Q4 + 4 * W4) {
        int wi = i - Q4;
        int w = wi >> 16;
        const float* W = (w == 0) ? Wq : (w == 1) ? Wk : (w == 2) ? Wv : Wp;
        float4 x = ((const float4*)W)[wi & (W4 - 1)];
        uint2 p;
        p.x = cvtpk_bf16(x.x, x.y);
        p.y = cvtpk_bf16(x.z, x.w);
        ((uint2*)w16)[wi] = p;
    } else {
        int bi = i - (Q4 + 4 * W4);
        if (bi < 512) {
            int seg = bi >> 7;
            int off = bi & 127;
            const float* B = (seg == 0) ? bq : (seg == 1) ? bk : (seg == 2) ? bv : bp;
            ((float4*)bcat)[bi] = ((const float4*)B)[off];
        }
    }
}

// Single-pass bf16 MFMA GEMM: C[m,c] = sum_k A[m,k]*W[c,k] + bias[c]
// MODE 0: B rows 0..1535 (Wq|Wk|Wv): scatter bf16 to q/k (split-head) and vt (transposed).
// MODE 1: fp32 out [m][512].
template<int MODE>
__global__ __launch_bounds__(256)
void mgemm(const ushort_t* __restrict__ A, const ushort_t* __restrict__ B,
           const float* __restrict__ bias,
           ushort_t* __restrict__ q_o, ushort_t* __restrict__ k_o,
           ushort_t* __restrict__ vt_o, float* __restrict__ p_o)
{
    __shared__ __align__(16) ushort_t As[128][40];
    __shared__ __align__(16) ushort_t Bs[128][40];

    const int t     = threadIdx.x;
    const int wid   = t >> 6;
    const int lane  = t & 63;
    const int lan16 = lane & 15;
    const int quad  = lane >> 4;
    const int wm    = (wid & 1) * 64;
    const int wn    = (wid >> 1) * 64;

    const int col0 = blockIdx.x * 128;
    const int row0 = blockIdx.y * 128;

    const int srow = t >> 1;
    const int skof = (t & 1) * 16;

    float4_t acc[4][4];
    #pragma unroll
    for (int i = 0; i < 4; i++)
        #pragma unroll
        for (int j = 0; j < 4; j++) acc[i][j] = (float4_t){0.f, 0.f, 0.f, 0.f};

    for (int k0 = 0; k0 < DM; k0 += 32) {
        const size_t aoff = (size_t)(row0 + srow) * DM + k0 + skof;
        const size_t boff = (size_t)(col0 + srow) * DM + k0 + skof;
        uint4 a0 = *(const uint4*)(A + aoff);
        uint4 a1 = *(const uint4*)(A + aoff + 8);
        uint4 b0 = *(const uint4*)(B + boff);
        uint4 b1 = *(const uint4*)(B + boff + 8);
        __syncthreads();
        *(uint4*)&As[srow][skof]     = a0;
        *(uint4*)&As[srow][skof + 8] = a1;
        *(uint4*)&Bs[srow][skof]     = b0;
        *(uint4*)&Bs[srow][skof + 8] = b1;
        __syncthreads();

        short8_t af[4], bf[4];
        #pragma unroll
        for (int i = 0; i < 4; i++) {
            af[i] = *(const short8_t*)&As[wm + i * 16 + lan16][quad * 8];
            bf[i] = *(const short8_t*)&Bs[wn + i * 16 + lan16][quad * 8];
        }
        #pragma unroll
        for (int i = 0; i < 4; i++)
            #pragma unroll
            for (int j = 0; j < 4; j++)
                acc[i][j] = __builtin_amdgcn_mfma_f32_16x16x32_bf16(af[i], bf[j], acc[i][j], 0, 0, 0);
    }

    #pragma unroll
    for (int j = 0; j < 4; j++) {
        int col = col0 + wn + j * 16 + lan16;
        float bv = bias[col];
        #pragma unroll
        for (int i = 0; i < 4; i++) {
            #pragma unroll
            for (int reg = 0; reg < 4; reg++) {
                int row = row0 + wm + i * 16 + quad * 4 + reg;
                float v = acc[i][j][reg] + bv;
                if (MODE == 0) {
                    int w = col >> 9;
                    int c = col & 511;
                    int hh = c & 7, dh = c >> 3;
                    int n = row >> 11, s = row & 2047;
                    if (w == 0)
                        q_o[(((size_t)(n * H_N + hh)) * SEQ + s) * DH + dh] = f2bf(v);
                    else if (w == 1)
                        k_o[(((size_t)(n * H_N + hh)) * SEQ + s) * DH + dh] = f2bf(v);
                    else
                        vt_o[(((size_t)(n * H_N + hh)) * DH + dh) * SEQ + s] = f2bf(v);
                } else {
                    p_o[(size_t)row * DM + col] = v;
                }
            }
        }
    }
}

// MFMA flash attention, S^T orientation, no-max softmax (scores provably bounded:
// scale <= exp(log10)/sqrt(512), |q.k| small => exp2 arg bounded, l <= ~1e6).
// Block = (n, h, 128 q-rows); 4 waves, wave owns 32 q-rows (2 B-frags of 16).
// S^T = K.Q^T  (C: col=lan16=qrow, row=quad*4+reg=key)
// O^T = V^T.P^T (C: col=lan16=qrow, row=quad*4+reg=dim)
__global__ __launch_bounds__(256)
void attn_k(const ushort_t* __restrict__ qw, const ushort_t* __restrict__ kw,
            const ushort_t* __restrict__ vt, const float* __restrict__ lsc,
            const float* __restrict__ rpe, ushort_t* __restrict__ ctx)
{
    __shared__ __align__(16) ushort_t K_s[64][72];          // [key][dim]
    __shared__ __align__(16) ushort_t VT_s[64][72];         // [dim][key]
    __shared__ __align__(16) unsigned int Pp[4][2][16][36]; // [wave][qf][qrow16][key-pair]
    __shared__ float tbl[2176];                             // sigmoid(rpe)*log2e, reversed

    const int t     = threadIdx.x;
    const int wid   = t >> 6;
    const int lane  = t & 63;
    const int lan16 = lane & 15;
    const int quad  = lane >> 4;

    const int qt = blockIdx.x;    // 0..15
    const int h  = blockIdx.y;
    const int n  = blockIdx.z;
    const int q0 = qt * 128;

    const size_t headoff = ((size_t)(n * H_N + h)) * SEQ * DH;
    const ushort_t* qh  = qw + headoff;
    const ushort_t* kh  = kw + headoff;
    const ushort_t* vth = vt + headoff;

    float ls = lsc[h];
    const float lm = 4.60517018598809136804f;   // log(100)
    if (ls > lm) ls = lm;
    const float scale2 = __expf(ls) * 0.04419417382415921757f * LOG2E;

    // bias table: tbl[w] = log2e * sigmoid(rpe[v]), v = q0 + 2174 - w (reversed ->
    // per-lane lookup addresses ascend with key). w in [0, 2174].
    for (int w = t; w < 2175; w += 256) {
        int v = q0 + 2174 - w;
        float x = rpe[v * H_N + h];
        tbl[w] = LOG2E / (1.0f + __expf(-x));
    }

    // Q as B-operand: lane lan16 = qrow, holds d = half*32+quad*8..+7
    short8_t qb[2][2];
    #pragma unroll
    for (int qf = 0; qf < 2; qf++) {
        const ushort_t* src = qh + (size_t)(q0 + wid * 32 + qf * 16 + lan16) * DH + quad * 8;
        qb[qf][0] = *(const short8_t*)(src);
        qb[qf][1] = *(const short8_t*)(src + 32);
    }

    float l_run[2] = {0.f, 0.f};
    float4_t o[4][2];   // [dim-sub][qf]
    #pragma unroll
    for (int ds = 0; ds < 4; ds++)
        #pragma unroll
        for (int qf = 0; qf < 2; qf++) o[ds][qf] = (float4_t){0.f, 0.f, 0.f, 0.f};

    const int key_st = t >> 2;
    const int part   = t & 3;

    for (int j0 = 0; j0 < SEQ; j0 += 64) {
        __syncthreads();   // prev-tile readers of K_s/VT_s done (also covers tbl build)
        {
            const ushort_t* ksrc = kh + (size_t)(j0 + key_st) * DH + part * 16;
            *(uint4*)&K_s[key_st][part * 16]     = *(const uint4*)(ksrc);
            *(uint4*)&K_s[key_st][part * 16 + 8] = *(const uint4*)(ksrc + 8);
            const ushort_t* vsrc = vth + (size_t)key_st * SEQ + j0 + part * 16;
            *(uint4*)&VT_s[key_st][part * 16]     = *(const uint4*)(vsrc);
            *(uint4*)&VT_s[key_st][part * 16 + 8] = *(const uint4*)(vsrc + 8);
        }
        __syncthreads();

        // ---- S^T = K.Q^T : per wave [64 keys x 32 qrows]
        float4_t st[4][2];
        #pragma unroll
        for (int sub = 0; sub < 4; sub++) {
            const ushort_t* kp = &K_s[sub * 16 + lan16][quad * 8];
            short8_t ka0 = *(const short8_t*)(kp);
            short8_t ka1 = *(const short8_t*)(kp + 32);
            #pragma unroll
            for (int qf = 0; qf < 2; qf++) {
                float4_t a = (float4_t){0.f, 0.f, 0.f, 0.f};
                a = __builtin_amdgcn_mfma_f32_16x16x32_bf16(ka0, qb[qf][0], a, 0, 0, 0);
                a = __builtin_amdgcn_mfma_f32_16x16x32_bf16(ka1, qb[qf][1], a, 0, 0, 0);
                st[sub][qf] = a;
            }
        }

        // ---- no-max softmax: lane owns row q0+wid*32+qf*16+lan16; keys sub*16+quad*4+reg
        #pragma unroll
        for (int qf = 0; qf < 2; qf++) {
            const int wbase = 127 - (wid * 32 + qf * 16 + lan16) + j0 + quad * 4;
            float ps = 0.f;
            #pragma unroll
            for (int sub = 0; sub < 4; sub++) {
                float e0 = fexp2(st[sub][qf][0] * scale2 + tbl[wbase + sub * 16 + 0]);
                float e1 = fexp2(st[sub][qf][1] * scale2 + tbl[wbase + sub * 16 + 1]);
                float e2 = fexp2(st[sub][qf][2] * scale2 + tbl[wbase + sub * 16 + 2]);
                float e3 = fexp2(st[sub][qf][3] * scale2 + tbl[wbase + sub * 16 + 3]);
                ps += (e0 + e1) + (e2 + e3);
                Pp[wid][qf][lan16][sub * 8 + quad * 2]     = cvtpk_bf16(e0, e1);
                Pp[wid][qf][lan16][sub * 8 + quad * 2 + 1] = cvtpk_bf16(e2, e3);
            }
            l_run[qf] += ps;
        }
        asm volatile("s_waitcnt lgkmcnt(0)" ::: "memory");  // wave-private Pp, no barrier

        // ---- O^T += V^T.P^T
        #pragma unroll
        for (int ks = 0; ks < 2; ks++) {
            short8_t pb[2];
            #pragma unroll
            for (int qf = 0; qf < 2; qf++)
                pb[qf] = *(const short8_t*)&Pp[wid][qf][lan16][ks * 16 + quad * 4];
            #pragma unroll
            for (int ds = 0; ds < 4; ds++) {
                short8_t va = *(const short8_t*)&VT_s[ds * 16 + lan16][ks * 32 + quad * 8];
                #pragma unroll
                for (int qf = 0; qf < 2; qf++)
                    o[ds][qf] = __builtin_amdgcn_mfma_f32_16x16x32_bf16(va, pb[qf], o[ds][qf], 0, 0, 0);
            }
        }
    }

    // epilogue: reduce l across quads; O^T col=lan16=qrow, row=quad*4+reg=dim; bf16 ctx
    #pragma unroll
    for (int qf = 0; qf < 2; qf++) {
        float l = l_run[qf];
        l += __shfl_xor(l, 16);
        l += __shfl_xor(l, 32);
        float inv = 1.0f / l;
        int row = q0 + wid * 32 + qf * 16 + lan16;
        size_t base = ((size_t)n * SEQ + row) * DM + h * DH;
        #pragma unroll
        for (int ds = 0; ds < 4; ds++) {
            uint2 p;
            p.x = cvtpk_bf16(o[ds][qf][0] * inv, o[ds][qf][1] * inv);
            p.y = cvtpk_bf16(o[ds][qf][2] * inv, o[ds][qf][3] * inv);
            *(uint2*)(ctx + base + ds * 16 + quad * 4) = p;
        }
    }
}

extern "C" void kernel_launch(void* const* d_in, const int* in_sizes, int n_in,
                              void* d_out, int out_size, void* d_ws, size_t ws_size,
                              hipStream_t stream) {
    const float* query = (const float*)d_in[0];
    const float* Wq  = (const float*)d_in[1];
    const float* bq  = (const float*)d_in[2];
    const float* Wk  = (const float*)d_in[3];
    const float* bk  = (const float*)d_in[4];
    const float* Wv  = (const float*)d_in[5];
    const float* bv  = (const float*)d_in[6];
    const float* Wp  = (const float*)d_in[7];
    const float* bp  = (const float*)d_in[8];
    const float* lsc = (const float*)d_in[9];
    const float* rpe = (const float*)d_in[10];

    const size_t QEL = (size_t)N_B * SEQ * DM;     // 4,194,304
    const size_t WEL = (size_t)DM * DM;            // 262,144
    char* ws = (char*)d_ws;
    ushort_t* q16  = (ushort_t*)(ws);              // bf16 query
    ushort_t* w16  = q16 + QEL;                    // Wq|Wk|Wv|Wp bf16
    float*    bcat = (float*)(w16 + 4 * WEL);      // 2048 floats
    ushort_t* qb   = (ushort_t*)(bcat + 2048);
    ushort_t* kb   = qb + QEL;
    ushort_t* vtb  = kb + QEL;
    ushort_t* ctx  = vtb + QEL;

    prep<<<(Q4 + 4 * W4 + 512 + 255) / 256, 256, 0, stream>>>(
        query, Wq, Wk, Wv, Wp, bq, bk, bv, bp, q16, w16, bcat);

    dim3 g1(1536 / 128, (N_B * SEQ) / 128);        // (12, 64)
    mgemm<0><<<g1, 256, 0, stream>>>(q16, w16, bcat, qb, kb, vtb, nullptr);

    dim3 ga(SEQ / 128, H_N, N_B);                  // (16, 8, 4)
    attn_k<<<ga, 256, 0, stream>>>(qb, kb, vtb, lsc, rpe, ctx);

    dim3 g2(DM / 128, (N_B * SEQ) / 128);          // (4, 64)
    mgemm<1><<<g2, 256, 0, stream>>>(ctx, w16 + 3 * WEL, bcat + 1536,
                                     nullptr, nullptr, nullptr, (float*)d_out);
}